// Round 11
// baseline (606.607 us; speedup 1.0000x reference)
//
#include <hip/hip_runtime.h>
#include <cstdint>
#include <cstdio>

typedef unsigned short u16;
typedef short bf16x8 __attribute__((ext_vector_type(8)));
typedef float f32x4 __attribute__((ext_vector_type(4)));
typedef unsigned short u16x8 __attribute__((ext_vector_type(8)));

#define SEQL 2048
#define NHEADS 32
#define HDIM 128
#define HIDDEN 4096

__device__ __forceinline__ u16 f2bf(float x){
  union { float f; unsigned u; } v; v.f = x;
  unsigned r = v.u + 0x7fffu + ((v.u >> 16) & 1u);
  return (u16)(r >> 16);
}
__device__ __forceinline__ float bf2f(u16 x){
  union { unsigned u; float f; } v; v.u = ((unsigned)x) << 16;
  return v.f;
}
__device__ __forceinline__ float exp2_asm(float x){
  float r; asm("v_exp_f32 %0, %1" : "=v"(r) : "v"(x)); return r;
}
__device__ __forceinline__ unsigned cvtpk_bf16(float lo, float hi){
  unsigned r; asm("v_cvt_pk_bf16_f32 %0, %1, %2" : "=v"(r) : "v"(lo), "v"(hi)); return r;
}

__device__ __forceinline__ void gload_lds16(const u16* g, u16* l){
  __builtin_amdgcn_global_load_lds((const __attribute__((address_space(1))) void*)g,
                                   (__attribute__((address_space(3))) void*)l, 16, 0, 0);
}

// ---------------- cast hidden_states f32 -> bf16 ----------------
__global__ void cast_hs_kernel(const float* __restrict__ in, u16* __restrict__ out, int n8){
  int i = blockIdx.x * blockDim.x + threadIdx.x;
  if (i >= n8) return;
  const float4* p = (const float4*)in + (size_t)i*2;
  float4 a = p[0], b = p[1];
  u16x8 o;
  o[0]=f2bf(a.x); o[1]=f2bf(a.y); o[2]=f2bf(a.z); o[3]=f2bf(a.w);
  o[4]=f2bf(b.x); o[5]=f2bf(b.y); o[6]=f2bf(b.z); o[7]=f2bf(b.w);
  *((u16x8*)out + i) = o;
}

// ---------------- transpose + cast weight chunk: W[K][Ntot] f32 -> Wt[n][k] bf16 ----------------
__global__ void wtrans_kernel(const float* __restrict__ W, u16* __restrict__ Wt,
                              int Ntot, int n0, int K){
  __shared__ float t[32][33];
  int tx = threadIdx.x, ty = threadIdx.y;
  int nn = blockIdx.x*32, k0 = blockIdx.y*32;
  #pragma unroll
  for (int i=0;i<4;i++)
    t[ty*4+i][tx] = W[(size_t)(k0+ty*4+i)*Ntot + n0 + nn + tx];
  __syncthreads();
  #pragma unroll
  for (int i=0;i<4;i++)
    Wt[(size_t)(nn+ty*4+i)*K + k0 + tx] = f2bf(t[tx][ty*4+i]);
}

// ---------------- 8-phase 256x256 GEMM (refcheck-passed; exact-round grids only) ----------------
template<int OUT_BF16>
__global__ __launch_bounds__(512, 2) void gemm8_kernel(const u16* __restrict__ A, const u16* __restrict__ Bt,
                              const float* __restrict__ bias, void* __restrict__ Cv,
                              int K, int ldC)
{
  extern __shared__ u16 lds[];   // 65536 u16 = 131072 B
  int tid = threadIdx.x;
  int lane = tid & 63;
  int wave = tid >> 6;
  int lr = lane & 15, lg = lane >> 4;
  int wm = wave >> 2, wn = wave & 3;

  int nwg = gridDim.x;
  int cpx = nwg >> 3;
  int b0 = blockIdx.x;
  int swz = (b0 & 7) * cpx + (b0 >> 3);
  int bm = swz & 7, bn = swz >> 3;      // compact: 8 bm fast, bn slow
  int m0 = bm * 256, n0 = bn * 256;
  int NT = K >> 6;

  int r0 = tid >> 3;
  int cb0 = ((tid & 7) ^ (r0 & 7)) * 8;

  const u16* A0p = A  + (size_t)m0*K;
  const u16* A1p = A  + (size_t)(m0+128)*K;
  const u16* B0p = Bt + (size_t)n0*K;
  const u16* B1p = Bt + (size_t)(n0+128)*K;

  #define STAGE8(G, SLOT) do {                                        \
    gload_lds16((G) + (size_t)r0*K + cb0, lds + (SLOT) + tid*8);      \
    gload_lds16((G) + (size_t)(r0+64)*K + cb0, lds + (SLOT) + (tid+512)*8); \
  } while(0)

  int x7 = lr & 7;
  int colk0 = (lg ^ x7)*8;
  int colk1 = ((4 + lg) ^ x7)*8;
  int rA[4], rB[2];
  #pragma unroll
  for (int f=0; f<4; f++) rA[f] = (wm*64 + f*16 + lr)*64;
  #pragma unroll
  for (int nf=0; nf<2; nf++) rB[nf] = (wn*32 + nf*16 + lr)*64;

  f32x4 acc[8][4] = {};
  bf16x8 a_[4][2], b0r[2][2], b1r[2][2];

  STAGE8(A0p,      0);
  STAGE8(B0p,   8192);
  STAGE8(B1p,  16384);
  STAGE8(A1p,  24576);
  STAGE8(A0p + 64, 32768);
  STAGE8(B0p + 64, 40960);
  STAGE8(B1p + 64, 49152);
  asm volatile("s_waitcnt vmcnt(6)" ::: "memory");
  asm volatile("s_barrier" ::: "memory");

  for (int T = 0; T < NT; ++T){
    int d = (T & 1) << 15;
    int e = d ^ 32768;
    const u16* sA0 = lds + d;
    const u16* sB0 = lds + d + 8192;
    const u16* sB1 = lds + d + 16384;
    const u16* sA1 = lds + d + 24576;
    int kc  = (T+1) << 6;
    int kc2 = (T+2) << 6;
    bool st2 = (T+2) < NT;

    // ---- phase q0 ----
    #pragma unroll
    for (int f=0; f<4; f++){
      a_[f][0] = *(const bf16x8*)&sA0[rA[f] + colk0];
      a_[f][1] = *(const bf16x8*)&sA0[rA[f] + colk1];
    }
    #pragma unroll
    for (int nf=0; nf<2; nf++){
      b0r[nf][0] = *(const bf16x8*)&sB0[rB[nf] + colk0];
      b0r[nf][1] = *(const bf16x8*)&sB0[rB[nf] + colk1];
    }
    if (T+1 < NT) STAGE8(A1p + kc, e + 24576);
    asm volatile("s_barrier" ::: "memory");
    asm volatile("s_waitcnt lgkmcnt(0)" ::: "memory");
    __builtin_amdgcn_sched_barrier(0);
    __builtin_amdgcn_s_setprio(1);
    #pragma unroll
    for (int f=0; f<4; f++){
      #pragma unroll
      for (int nf=0; nf<2; nf++){
        acc[f][nf] = __builtin_amdgcn_mfma_f32_16x16x32_bf16(a_[f][0], b0r[nf][0], acc[f][nf], 0, 0, 0);
        acc[f][nf] = __builtin_amdgcn_mfma_f32_16x16x32_bf16(a_[f][1], b0r[nf][1], acc[f][nf], 0, 0, 0);
      }
    }
    __builtin_amdgcn_s_setprio(0);
    asm volatile("s_barrier" ::: "memory");

    // ---- phase q1 ----
    #pragma unroll
    for (int nf=0; nf<2; nf++){
      b1r[nf][0] = *(const bf16x8*)&sB1[rB[nf] + colk0];
      b1r[nf][1] = *(const bf16x8*)&sB1[rB[nf] + colk1];
    }
    if (st2) STAGE8(A0p + kc2, d);
    asm volatile("s_barrier" ::: "memory");
    asm volatile("s_waitcnt lgkmcnt(0)" ::: "memory");
    __builtin_amdgcn_sched_barrier(0);
    __builtin_amdgcn_s_setprio(1);
    #pragma unroll
    for (int f=0; f<4; f++){
      #pragma unroll
      for (int nf=0; nf<2; nf++){
        acc[f][2+nf] = __builtin_amdgcn_mfma_f32_16x16x32_bf16(a_[f][0], b1r[nf][0], acc[f][2+nf], 0, 0, 0);
        acc[f][2+nf] = __builtin_amdgcn_mfma_f32_16x16x32_bf16(a_[f][1], b1r[nf][1], acc[f][2+nf], 0, 0, 0);
      }
    }
    __builtin_amdgcn_s_setprio(0);
    asm volatile("s_barrier" ::: "memory");

    // ---- phase q2 ----
    #pragma unroll
    for (int f=0; f<4; f++){
      a_[f][0] = *(const bf16x8*)&sA1[rA[f] + colk0];
      a_[f][1] = *(const bf16x8*)&sA1[rA[f] + colk1];
    }
    if (st2) STAGE8(B0p + kc2, d + 8192);
    asm volatile("s_barrier" ::: "memory");
    asm volatile("s_waitcnt lgkmcnt(0)" ::: "memory");
    __builtin_amdgcn_sched_barrier(0);
    __builtin_amdgcn_s_setprio(1);
    #pragma unroll
    for (int f=0; f<4; f++){
      #pragma unroll
      for (int nf=0; nf<2; nf++){
        acc[4+f][2+nf] = __builtin_amdgcn_mfma_f32_16x16x32_bf16(a_[f][0], b1r[nf][0], acc[4+f][2+nf], 0, 0, 0);
        acc[4+f][2+nf] = __builtin_amdgcn_mfma_f32_16x16x32_bf16(a_[f][1], b1r[nf][1], acc[4+f][2+nf], 0, 0, 0);
      }
    }
    __builtin_amdgcn_s_setprio(0);
    asm volatile("s_barrier" ::: "memory");

    // ---- phase q3 ----
    if (st2) STAGE8(B1p + kc2, d + 16384);
    __builtin_amdgcn_s_setprio(1);
    #pragma unroll
    for (int f=0; f<4; f++){
      #pragma unroll
      for (int nf=0; nf<2; nf++){
        acc[4+f][nf] = __builtin_amdgcn_mfma_f32_16x16x32_bf16(a_[f][0], b0r[nf][0], acc[4+f][nf], 0, 0, 0);
        acc[4+f][nf] = __builtin_amdgcn_mfma_f32_16x16x32_bf16(a_[f][1], b0r[nf][1], acc[4+f][nf], 0, 0, 0);
      }
    }
    __builtin_amdgcn_s_setprio(0);
    if (T+1 < NT){
      if (st2) asm volatile("s_waitcnt vmcnt(6)" ::: "memory");
      else     asm volatile("s_waitcnt vmcnt(0)" ::: "memory");
    }
    asm volatile("s_barrier" ::: "memory");
  }
  #undef STAGE8

  #pragma unroll
  for (int mh=0; mh<2; mh++){
    #pragma unroll
    for (int f=0; f<4; f++){
      #pragma unroll
      for (int nh=0; nh<2; nh++){
        #pragma unroll
        for (int nf=0; nf<2; nf++){
          #pragma unroll
          for (int jj=0; jj<4; jj++){
            int gr = m0 + mh*128 + wm*64 + f*16 + lg*4 + jj;
            int gc = n0 + nh*128 + wn*32 + nf*16 + lr;
            float v = acc[mh*4+f][nh*2+nf][jj] + bias[gc];
            if (OUT_BF16) ((u16*)Cv)[(size_t)gr*ldC + gc] = f2bf(v);
            else          ((float*)Cv)[(size_t)gr*ldC + gc] = v;
          }
        }
      }
    }
  }
}

// ---------------- pipelined GEMM: BM=128,BN=256,BK=64, 2-phase, 3-deep ----------------
template<int OUT_BF16>
__global__ __launch_bounds__(512) void gemm3_kernel(const u16* __restrict__ A, const u16* __restrict__ Bt,
                              const float* __restrict__ bias, void* __restrict__ Cv,
                              int K, int ldC, int NBM)
{
  extern __shared__ u16 lds[];   // 3 * 24576 u16 = 147456 B
  int tid = threadIdx.x;
  int lane = tid & 63;
  int wave = tid >> 6;
  int lr = lane & 15, lg = lane >> 4;
  int wm = wave >> 2, wn = wave & 3;

  int nwg = gridDim.x;
  int cpx = nwg >> 3;
  int b0 = blockIdx.x;
  int swz = (b0 & 7) * cpx + (b0 >> 3);
  int bm = swz % NBM, bn = swz / NBM;
  int m0 = bm * 128, n0 = bn * 256;

  int NT = K >> 6;

  unsigned offA[2]; int ldsA[2];
  #pragma unroll
  for (int i=0;i<2;i++){
    int c = tid + i*512;
    int row = c >> 3, blk = c & 7;
    offA[i] = (unsigned)(m0 + row)*K + (unsigned)((blk ^ (row & 7))*8);
    ldsA[i] = c*8;
  }
  unsigned offB[4]; int ldsB[4];
  #pragma unroll
  for (int i=0;i<4;i++){
    int c = tid + i*512;
    int row = c >> 3, blk = c & 7;
    offB[i] = (unsigned)(n0 + row)*K + (unsigned)((blk ^ (row & 7))*8);
    ldsB[i] = c*8;
  }

  int colk[2];
  colk[0] = ((lg)     ^ (lr & 7))*8;
  colk[1] = ((4 + lg) ^ (lr & 7))*8;
  int rA[4], rB[4];
  #pragma unroll
  for (int m=0;m<4;m++) rA[m] = (wm*64 + m*16 + lr)*64;
  #pragma unroll
  for (int n=0;n<4;n++) rB[n] = (wn*64 + n*16 + lr)*64;

  f32x4 acc[4][4] = {};

  #pragma unroll
  for (int tt=0; tt<2; ++tt){
    u16* dA = lds + tt*24576;
    u16* dB = dA + 8192;
    int k0 = tt*64;
    #pragma unroll
    for (int i=0;i<2;i++) gload_lds16(A + offA[i] + k0, dA + ldsA[i]);
    #pragma unroll
    for (int i=0;i<4;i++) gload_lds16(Bt + offB[i] + k0, dB + ldsB[i]);
  }
  asm volatile("s_waitcnt vmcnt(6)" ::: "memory");
  asm volatile("s_barrier" ::: "memory");

  int p = 0, s2 = 2;
  for (int t = 0; t < NT; ++t){
    const u16* bA = lds + p*24576;
    const u16* bB = bA + 8192;
    u16* dA = lds + s2*24576;
    u16* dB = dA + 8192;
    bool st = (t + 2) < NT;
    int k2 = (t + 2) << 6;

    bf16x8 a_[4][2], bf0[2][2];
    #pragma unroll
    for (int m=0;m<4;m++){
      a_[m][0] = *(const bf16x8*)&bA[rA[m] + colk[0]];
      a_[m][1] = *(const bf16x8*)&bA[rA[m] + colk[1]];
    }
    #pragma unroll
    for (int n=0;n<2;n++){
      bf0[n][0] = *(const bf16x8*)&bB[rB[n] + colk[0]];
      bf0[n][1] = *(const bf16x8*)&bB[rB[n] + colk[1]];
    }
    if (st){
      gload_lds16(A + offA[0] + k2, dA + ldsA[0]);
      gload_lds16(A + offA[1] + k2, dA + ldsA[1]);
      gload_lds16(Bt + offB[0] + k2, dB + ldsB[0]);
    }
    asm volatile("s_barrier" ::: "memory");
    asm volatile("s_waitcnt lgkmcnt(0)" ::: "memory");
    __builtin_amdgcn_sched_barrier(0);
    __builtin_amdgcn_s_setprio(1);
    #pragma unroll
    for (int m=0;m<4;m++){
      #pragma unroll
      for (int n=0;n<2;n++){
        acc[m][n] = __builtin_amdgcn_mfma_f32_16x16x32_bf16(a_[m][0], bf0[n][0], acc[m][n], 0, 0, 0);
        acc[m][n] = __builtin_amdgcn_mfma_f32_16x16x32_bf16(a_[m][1], bf0[n][1], acc[m][n], 0, 0, 0);
      }
    }
    __builtin_amdgcn_s_setprio(0);
    asm volatile("s_barrier" ::: "memory");

    bf16x8 bf1[2][2];
    #pragma unroll
    for (int n=0;n<2;n++){
      bf1[n][0] = *(const bf16x8*)&bB[rB[n+2] + colk[0]];
      bf1[n][1] = *(const bf16x8*)&bB[rB[n+2] + colk[1]];
    }
    if (st){
      gload_lds16(Bt + offB[1] + k2, dB + ldsB[1]);
      gload_lds16(Bt + offB[2] + k2, dB + ldsB[2]);
      gload_lds16(Bt + offB[3] + k2, dB + ldsB[3]);
    }
    asm volatile("s_barrier" ::: "memory");
    asm volatile("s_waitcnt lgkmcnt(0)" ::: "memory");
    __builtin_amdgcn_sched_barrier(0);
    __builtin_amdgcn_s_setprio(1);
    #pragma unroll
    for (int m=0;m<4;m++){
      #pragma unroll
      for (int n=0;n<2;n++){
        acc[m][n+2] = __builtin_amdgcn_mfma_f32_16x16x32_bf16(a_[m][0], bf1[n][0], acc[m][n+2], 0, 0, 0);
        acc[m][n+2] = __builtin_amdgcn_mfma_f32_16x16x32_bf16(a_[m][1], bf1[n][1], acc[m][n+2], 0, 0, 0);
      }
    }
    __builtin_amdgcn_s_setprio(0);
    if (st) asm volatile("s_waitcnt vmcnt(6)" ::: "memory");
    else    asm volatile("s_waitcnt vmcnt(0)" ::: "memory");
    asm volatile("s_barrier" ::: "memory");

    p = (p == 2) ? 0 : p + 1;
    s2 = (s2 == 2) ? 0 : s2 + 1;
  }

  #pragma unroll
  for (int m=0;m<4;m++){
    #pragma unroll
    for (int n=0;n<4;n++){
      #pragma unroll
      for (int j=0;j<4;j++){
        int gr = m0 + wm*64 + m*16 + lg*4 + j;
        int gc = n0 + wn*64 + n*16 + lr;
        float v = acc[m][n][j] + bias[gc];
        if (OUT_BF16) ((u16*)Cv)[(size_t)gr*ldC + gc] = f2bf(v);
        else          ((float*)Cv)[(size_t)gr*ldC + gc] = v;
      }
    }
  }
}

// ---------------- RoPE + relayout ----------------
__global__ __launch_bounds__(256) void rope_kernel(const u16* __restrict__ qkv, const int* __restrict__ pos,
                            u16* __restrict__ Q, u16* __restrict__ Kc, u16* __restrict__ V)
{
  int s = blockIdx.x*4 + (threadIdx.x >> 6);
  int h = blockIdx.y;
  int i = threadIdx.x & 63;
  int half = i >> 5, ii = i & 31;
  int d0 = half*64 + ii*2;
  const u16* base = qkv + (size_t)s*12288 + h*384;
  unsigned qp = *(const unsigned*)&base[d0];
  unsigned kp = *(const unsigned*)&base[128 + d0];
  unsigned vp = *(const unsigned*)&base[256 + d0];
  float qe = bf2f((u16)qp), qo = bf2f((u16)(qp >> 16));
  float ke = bf2f((u16)kp), ko = bf2f((u16)(kp >> 16));
  float pv = (float)(pos[half*SEQL + s] + 1);
  float fr = exp2f(-(float)ii * 0.4152410118609203f);  // 10000^(-ii/32)
  float ang = pv * fr;
  float sn, cs; sincosf(ang, &sn, &cs);
  const float sc = 0.1275174313f;  // (1/sqrt(128)) * log2(e), folded into Q
  float q0 = (qe*cs - qo*sn)*sc, q1 = (qe*sn + qo*cs)*sc;
  float k0 = ke*cs - ko*sn,      k1 = ke*sn + ko*cs;
  size_t ob = ((size_t)h*SEQL + s)*HDIM + d0;
  *(unsigned*)&Q[ob]  = (unsigned)f2bf(q0) | ((unsigned)f2bf(q1) << 16);
  *(unsigned*)&Kc[ob] = (unsigned)f2bf(k0) | ((unsigned)f2bf(k1) << 16);
  *(unsigned*)&V[ob]  = vp;
}

// ---------------- V -> V^T per head: [h][s][d] -> [h][d][s] ----------------
__global__ void vtrans_kernel(const u16* __restrict__ V, u16* __restrict__ Vt){
  __shared__ u16 t[32][33];
  int h = blockIdx.z;
  int d0 = blockIdx.x*32, s0 = blockIdx.y*32;
  int tx = threadIdx.x, ty = threadIdx.y;
  const u16* Vh = V + (size_t)h*SEQL*HDIM;
  u16* Vth = Vt + (size_t)h*HDIM*SEQL;
  #pragma unroll
  for (int i=0;i<4;i++)
    t[ty*4+i][tx] = Vh[(size_t)(s0+ty*4+i)*HDIM + d0 + tx];
  __syncthreads();
  #pragma unroll
  for (int i=0;i<4;i++)
    Vth[(size_t)(d0+ty*4+i)*SEQL + s0 + tx] = t[tx][ty*4+i];
}

// ---------------- causal flash attention v7 ----------------
// v6 structure, but NO K/V LDS staging at all: K/V are L2/L1-resident
// (1 MB/head); fragments read directly from global (16B aligned, 64B
// coalesced per lg-quad). P stays as per-wave LDS scratch (same-wave
// ordering, no barrier). ZERO __syncthreads; LDS 8.5KB -> high occupancy,
// whole grid co-resident; no prefetch machinery.
__global__ __launch_bounds__(256) void attn_kernel(const u16* __restrict__ Q, const u16* __restrict__ Kc,
                             const u16* __restrict__ Vt, u16* __restrict__ ctx)
{
  __shared__ u16 P[4*16*68];
  int qt = (gridDim.x - 1) - blockIdx.x;   // heavy blocks first
  int h = blockIdx.y;
  int tid = threadIdx.x;
  int lane = tid & 63;
  int wave = tid >> 6;
  int lr = lane & 15, lg = lane >> 4;
  int q0a = qt*128 + wave*16;
  int q0b = q0a + 64;
  int qa = q0a + lr, qb = q0b + lr;
  const u16* Qh = Q  + (size_t)h*SEQL*HDIM;
  const u16* Kh = Kc + (size_t)h*SEQL*HDIM;
  const u16* Vh = Vt + (size_t)h*HDIM*SEQL;
  u16* Pw = &P[wave*1088];

  bf16x8 qfa[4], qfb[4];
  #pragma unroll
  for (int k32=0;k32<4;k32++){
    qfa[k32] = *(const bf16x8*)&Qh[(size_t)(q0a+lr)*HDIM + k32*32 + lg*8];
    qfb[k32] = *(const bf16x8*)&Qh[(size_t)(q0b+lr)*HDIM + k32*32 + lg*8];
  }

  f32x4 oa[8] = {}, ob[8] = {};
  float ma = -1e30f, la = 0.f;
  float mb = -1e30f, lb = 0.f;

  int nt = (qt+1)*2;   // 64-key tiles

  #define SMAX(S4, O, MRUN, LRUN, QROW, Q0S, PA0, PA1) do {                 \
    float sv[16];                                                           \
    _Pragma("unroll")                                                       \
    for (int g=0;g<4;g++){                                                  \
      _Pragma("unroll")                                                     \
      for (int j=0;j<4;j++) sv[g*4+j] = S4[g][j];                           \
    }                                                                       \
    if (t0 + 63 > (Q0S)){   /* diagonal tile: apply causal mask */          \
      int kb = t0 + lg*4;                                                   \
      _Pragma("unroll")                                                     \
      for (int g=0;g<4;g++){                                                \
        _Pragma("unroll")                                                   \
        for (int j=0;j<4;j++)                                               \
          sv[g*4+j] = (kb + g*16 + j > (QROW)) ? -1e30f : sv[g*4+j];        \
      }                                                                     \
    }                                                                       \
    float mx = fmaxf(                                                       \
      fmaxf(fmaxf(fmaxf(sv[0],sv[1]),fmaxf(sv[2],sv[3])),                   \
            fmaxf(fmaxf(sv[4],sv[5]),fmaxf(sv[6],sv[7]))),                  \
      fmaxf(fmaxf(fmaxf(sv[8],sv[9]),fmaxf(sv[10],sv[11])),                 \
            fmaxf(fmaxf(sv[12],sv[13]),fmaxf(sv[14],sv[15]))));             \
    mx = fmaxf(mx, __shfl_xor(mx, 16));                                     \
    mx = fmaxf(mx, __shfl_xor(mx, 32));                                     \
    if (!__all(mx <= (MRUN) + 11.5415603f)){                                \
      float mnew = fmaxf((MRUN), mx);                                       \
      float scl = exp2_asm((MRUN) - mnew);                                  \
      (LRUN) *= scl;                                                        \
      (MRUN) = mnew;                                                        \
      float sj[4];                                                          \
      _Pragma("unroll")                                                     \
      for (int j=0;j<4;j++) sj[j] = __shfl(scl, lg*4 + j);                  \
      _Pragma("unroll")                                                     \
      for (int n=0;n<8;n++){                                                \
        _Pragma("unroll")                                                   \
        for (int j=0;j<4;j++) O[n][j] *= sj[j];                             \
      }                                                                     \
    }                                                                       \
    float pr[16];                                                           \
    _Pragma("unroll")                                                       \
    for (int i=0;i<16;i++) pr[i] = exp2_asm(sv[i] - (MRUN));                \
    float sm = (((pr[0]+pr[1]) + (pr[2]+pr[3])) + ((pr[4]+pr[5]) + (pr[6]+pr[7]))) \
             + (((pr[8]+pr[9]) + (pr[10]+pr[11])) + ((pr[12]+pr[13]) + (pr[14]+pr[15]))); \
    sm += __shfl_xor(sm, 16);                                               \
    sm += __shfl_xor(sm, 32);                                               \
    (LRUN) += sm;                                                           \
    _Pragma("unroll")                                                       \
    for (int g=0;g<4;g++){                                                  \
      uint2 w;                                                              \
      w.x = cvtpk_bf16(pr[g*4],   pr[g*4+1]);                               \
      w.y = cvtpk_bf16(pr[g*4+2], pr[g*4+3]);                               \
      *(uint2*)&Pw[lr*68 + g*16 + lg*4] = w;                                \
    }                                                                       \
    PA0 = *(const bf16x8*)&Pw[lr*68 + lg*8];                                \
    PA1 = *(const bf16x8*)&Pw[lr*68 + 32 + lg*8];                           \
  } while(0)

  for (int t = 0; t < nt; ++t){
    int t0 = t*64;
    const u16* Kt = Kh + (size_t)t0*HDIM;   // [64][128] rows, global
    bool ba = (t0 <= q0a + 15);             // strip-a active

    // ---- QK^T, K fragments straight from global (L1/L2) ----
    f32x4 s4a[4] = {}, s4b[4] = {};
    if (ba){
      #pragma unroll
      for (int g=0; g<4; g++){
        int r = g*16 + lr;
        #pragma unroll
        for (int k32=0;k32<4;k32++){
          bf16x8 kf = *(const bf16x8*)&Kt[(size_t)r*HDIM + (((k32<<2)|lg))*8];
          s4a[g] = __builtin_amdgcn_mfma_f32_16x16x32_bf16(kf, qfa[k32], s4a[g], 0, 0, 0);
          s4b[g] = __builtin_amdgcn_mfma_f32_16x16x32_bf16(kf, qfb[k32], s4b[g], 0, 0, 0);
        }
      }
    } else {
      #pragma unroll
      for (int g=0; g<4; g++){
        int r = g*16 + lr;
        #pragma unroll
        for (int k32=0;k32<4;k32++){
          bf16x8 kf = *(const bf16x8*)&Kt[(size_t)r*HDIM + (((k32<<2)|lg))*8];
          s4b[g] = __builtin_amdgcn_mfma_f32_16x16x32_bf16(kf, qfb[k32], s4b[g], 0, 0, 0);
        }
      }
    }

    // ---- softmax per strip; P per-wave scratch, same-wave ordering ----
    bf16x8 paa0, paa1, pab0, pab1;
    if (ba) SMAX(s4a, oa, ma, la, qa, q0a, paa0, paa1);
    SMAX(s4b, ob, mb, lb, qb, q0b, pab0, pab1);

    // ---- PV, V fragments straight from global (L1/L2), shared across strips ----
    if (ba){
      #pragma unroll
      for (int n=0;n<8;n++){
        int dd = n*16 + lr;
        bf16x8 v0 = *(const bf16x8*)&Vh[(size_t)dd*SEQL + t0 + lg*8];
        bf16x8 v1 = *(const bf16x8*)&Vh[(size_t)dd*SEQL + t0 + 32 + lg*8];
        oa[n] = __builtin_amdgcn_mfma_f32_16x16x32_bf16(paa0, v0, oa[n], 0, 0, 0);
        oa[n] = __builtin_amdgcn_mfma_f32_16x16x32_bf16(paa1, v1, oa[n], 0, 0, 0);
        ob[n] = __builtin_amdgcn_mfma_f32_16x16x32_bf16(pab0, v0, ob[n], 0, 0, 0);
        ob[n] = __builtin_amdgcn_mfma_f32_16x16x32_bf16(pab1, v1, ob[n], 0, 0, 0);
      }
    } else {
      #pragma unroll
      for (int n=0;n<8;n++){
        int dd = n*16 + lr;
        bf16x8 v0 = *(const bf16x8*)&Vh[(size_t)dd*SEQL + t0 + lg*8];
        bf16x8 v1 = *(const bf16x8*)&Vh[(size_t)dd*SEQL + t0 + 32 + lg*8];
        ob[n] = __builtin_amdgcn_mfma_f32_16x16x32_bf16(pab0, v0, ob[n], 0, 0, 0);
        ob[n] = __builtin_amdgcn_mfma_f32_16x16x32_bf16(pab1, v1, ob[n], 0, 0, 0);
      }
    }
  }
  #undef SMAX

  #pragma unroll
  for (int j=0;j<4;j++){
    float lja = __shfl(la, lg*4 + j);
    float inva = 1.f / lja;
    int srowa = q0a + lg*4 + j;
    #pragma unroll
    for (int n=0;n<8;n++)
      ctx[(size_t)srowa*HIDDEN + h*HDIM + n*16 + lr] = f2bf(oa[n][j]*inva);
    float ljb = __shfl(lb, lg*4 + j);
    float invb = 1.f / ljb;
    int srowb = q0b + lg*4 + j;
    #pragma unroll
    for (int n=0;n<8;n++)
      ctx[(size_t)srowb*HIDDEN + h*HDIM + n*16 + lr] = f2bf(ob[n][j]*invb);
  }
}

extern "C" void kernel_launch(void* const* d_in, const int* in_sizes, int n_in,
                              void* d_out, int out_size, void* d_ws, size_t ws_size,
                              hipStream_t stream)
{
  const float* hs   = (const float*)d_in[0];
  const int*   pos  = (const int*)d_in[1];
  const float* Wqkv = (const float*)d_in[2];
  const float* bqkv = (const float*)d_in[3];
  const float* Wd   = (const float*)d_in[4];
  const float* bd   = (const float*)d_in[5];

  const size_t o_hs  = 0;
  const size_t o_qkv = 16777216;
  const size_t o_Wtq = 67108864;
  const size_t o_Q   = 67108864;
  const size_t o_K   = 83886080;
  const size_t o_V   = 100663296;
  const size_t o_Vt  = 117440512;
  const size_t o_Wtd = 134217728;
  const size_t need  = 167772160;
  if (ws_size < need){
    fprintf(stderr, "kernel_launch: ws too small: %zu < %zu\n", ws_size, need);
    return;
  }
  char* w = (char*)d_ws;
  u16* hsb = (u16*)(w + o_hs);
  u16* qkv = (u16*)(w + o_qkv);
  u16* ctx = (u16*)(w + o_qkv);
  u16* Wtq = (u16*)(w + o_Wtq);
  u16* Qs  = (u16*)(w + o_Q);
  u16* Ks  = (u16*)(w + o_K);
  u16* Vs  = (u16*)(w + o_V);
  u16* Vts = (u16*)(w + o_Vt);
  u16* Wtd = (u16*)(w + o_Wtd);

  const size_t g8_lds = 65536*sizeof(u16);     // 131072 B
  const size_t g3_lds = 3*24576*sizeof(u16);   // 147456 B

  cast_hs_kernel<<<dim3(4096), dim3(256), 0, stream>>>(hs, hsb, SEQL*HIDDEN/8);
  wtrans_kernel<<<dim3(384,128), dim3(32,8), 0, stream>>>(Wqkv, Wtq, 12288, 0, 4096);

  // QKV GEMM split for exact CU-rounds:
  gemm8_kernel<1><<<dim3(8*32), dim3(512), g8_lds, stream>>>(
      hsb, Wtq, bqkv, (void*)qkv, HIDDEN, 12288);
  gemm3_kernel<1><<<dim3(16*16), dim3(512), g3_lds, stream>>>(
      hsb, Wtq + (size_t)8192*HIDDEN, bqkv + 8192, (void*)(qkv + 8192),
      HIDDEN, 12288, 16);

  wtrans_kernel<<<dim3(128,128), dim3(32,8), 0, stream>>>(Wd, Wtd, 4096, 0, 4096);

  rope_kernel<<<dim3(SEQL/4, NHEADS), dim3(256), 0, stream>>>(qkv, pos, Qs, Ks, Vs);
  vtrans_kernel<<<dim3(4, 64, NHEADS), dim3(32,8), 0, stream>>>(Vs, Vts);
  attn_kernel<<<dim3(SEQL/128, NHEADS), dim3(256), 0, stream>>>(Qs, Ks, Vts, ctx);

  // dense GEMM: [2048 x 4096] x [4096 x 4096]^T -> d_out f32 (1 exact CU-round)
  gemm3_kernel<0><<<dim3(16*16), dim3(512), g3_lds, stream>>>(
      ctx, Wtd, bd, d_out, HIDDEN, HIDDEN, 16);
}

// Round 12
// 451.117 us; speedup vs baseline: 1.3447x; 1.3447x over previous
//
#include <hip/hip_runtime.h>
#include <cstdint>
#include <cstdio>

typedef unsigned short u16;
typedef short bf16x8 __attribute__((ext_vector_type(8)));
typedef float f32x4 __attribute__((ext_vector_type(4)));
typedef unsigned short u16x8 __attribute__((ext_vector_type(8)));

#define SEQL 2048
#define NHEADS 32
#define HDIM 128
#define HIDDEN 4096

__device__ __forceinline__ u16 f2bf(float x){
  union { float f; unsigned u; } v; v.f = x;
  unsigned r = v.u + 0x7fffu + ((v.u >> 16) & 1u);
  return (u16)(r >> 16);
}
__device__ __forceinline__ float bf2f(u16 x){
  union { unsigned u; float f; } v; v.u = ((unsigned)x) << 16;
  return v.f;
}
__device__ __forceinline__ float exp2_asm(float x){
  float r; asm("v_exp_f32 %0, %1" : "=v"(r) : "v"(x)); return r;
}
__device__ __forceinline__ unsigned cvtpk_bf16(float lo, float hi){
  unsigned r; asm("v_cvt_pk_bf16_f32 %0, %1, %2" : "=v"(r) : "v"(lo), "v"(hi)); return r;
}

__device__ __forceinline__ void gload_lds16(const u16* g, u16* l){
  __builtin_amdgcn_global_load_lds((const __attribute__((address_space(1))) void*)g,
                                   (__attribute__((address_space(3))) void*)l, 16, 0, 0);
}

// ---------------- cast hidden_states f32 -> bf16 ----------------
__global__ void cast_hs_kernel(const float* __restrict__ in, u16* __restrict__ out, int n8){
  int i = blockIdx.x * blockDim.x + threadIdx.x;
  if (i >= n8) return;
  const float4* p = (const float4*)in + (size_t)i*2;
  float4 a = p[0], b = p[1];
  u16x8 o;
  o[0]=f2bf(a.x); o[1]=f2bf(a.y); o[2]=f2bf(a.z); o[3]=f2bf(a.w);
  o[4]=f2bf(b.x); o[5]=f2bf(b.y); o[6]=f2bf(b.z); o[7]=f2bf(b.w);
  *((u16x8*)out + i) = o;
}

// ---------------- transpose + cast weight chunk: W[K][Ntot] f32 -> Wt[n][k] bf16 ----------------
__global__ void wtrans_kernel(const float* __restrict__ W, u16* __restrict__ Wt,
                              int Ntot, int n0, int K){
  __shared__ float t[32][33];
  int tx = threadIdx.x, ty = threadIdx.y;
  int nn = blockIdx.x*32, k0 = blockIdx.y*32;
  #pragma unroll
  for (int i=0;i<4;i++)
    t[ty*4+i][tx] = W[(size_t)(k0+ty*4+i)*Ntot + n0 + nn + tx];
  __syncthreads();
  #pragma unroll
  for (int i=0;i<4;i++)
    Wt[(size_t)(nn+ty*4+i)*K + k0 + tx] = f2bf(t[tx][ty*4+i]);
}

// ---------------- 8-phase 256x256 GEMM (refcheck-passed; exact-round grids only) ----------------
template<int OUT_BF16>
__global__ __launch_bounds__(512, 2) void gemm8_kernel(const u16* __restrict__ A, const u16* __restrict__ Bt,
                              const float* __restrict__ bias, void* __restrict__ Cv,
                              int K, int ldC)
{
  extern __shared__ u16 lds[];   // 65536 u16 = 131072 B
  int tid = threadIdx.x;
  int lane = tid & 63;
  int wave = tid >> 6;
  int lr = lane & 15, lg = lane >> 4;
  int wm = wave >> 2, wn = wave & 3;

  int nwg = gridDim.x;
  int cpx = nwg >> 3;
  int b0 = blockIdx.x;
  int swz = (b0 & 7) * cpx + (b0 >> 3);
  int bm = swz & 7, bn = swz >> 3;      // compact: 8 bm fast, bn slow
  int m0 = bm * 256, n0 = bn * 256;
  int NT = K >> 6;

  int r0 = tid >> 3;
  int cb0 = ((tid & 7) ^ (r0 & 7)) * 8;

  const u16* A0p = A  + (size_t)m0*K;
  const u16* A1p = A  + (size_t)(m0+128)*K;
  const u16* B0p = Bt + (size_t)n0*K;
  const u16* B1p = Bt + (size_t)(n0+128)*K;

  #define STAGE8(G, SLOT) do {                                        \
    gload_lds16((G) + (size_t)r0*K + cb0, lds + (SLOT) + tid*8);      \
    gload_lds16((G) + (size_t)(r0+64)*K + cb0, lds + (SLOT) + (tid+512)*8); \
  } while(0)

  int x7 = lr & 7;
  int colk0 = (lg ^ x7)*8;
  int colk1 = ((4 + lg) ^ x7)*8;
  int rA[4], rB[2];
  #pragma unroll
  for (int f=0; f<4; f++) rA[f] = (wm*64 + f*16 + lr)*64;
  #pragma unroll
  for (int nf=0; nf<2; nf++) rB[nf] = (wn*32 + nf*16 + lr)*64;

  f32x4 acc[8][4] = {};
  bf16x8 a_[4][2], b0r[2][2], b1r[2][2];

  STAGE8(A0p,      0);
  STAGE8(B0p,   8192);
  STAGE8(B1p,  16384);
  STAGE8(A1p,  24576);
  STAGE8(A0p + 64, 32768);
  STAGE8(B0p + 64, 40960);
  STAGE8(B1p + 64, 49152);
  asm volatile("s_waitcnt vmcnt(6)" ::: "memory");
  asm volatile("s_barrier" ::: "memory");

  for (int T = 0; T < NT; ++T){
    int d = (T & 1) << 15;
    int e = d ^ 32768;
    const u16* sA0 = lds + d;
    const u16* sB0 = lds + d + 8192;
    const u16* sB1 = lds + d + 16384;
    const u16* sA1 = lds + d + 24576;
    int kc  = (T+1) << 6;
    int kc2 = (T+2) << 6;
    bool st2 = (T+2) < NT;

    // ---- phase q0 ----
    #pragma unroll
    for (int f=0; f<4; f++){
      a_[f][0] = *(const bf16x8*)&sA0[rA[f] + colk0];
      a_[f][1] = *(const bf16x8*)&sA0[rA[f] + colk1];
    }
    #pragma unroll
    for (int nf=0; nf<2; nf++){
      b0r[nf][0] = *(const bf16x8*)&sB0[rB[nf] + colk0];
      b0r[nf][1] = *(const bf16x8*)&sB0[rB[nf] + colk1];
    }
    if (T+1 < NT) STAGE8(A1p + kc, e + 24576);
    asm volatile("s_barrier" ::: "memory");
    asm volatile("s_waitcnt lgkmcnt(0)" ::: "memory");
    __builtin_amdgcn_sched_barrier(0);
    __builtin_amdgcn_s_setprio(1);
    #pragma unroll
    for (int f=0; f<4; f++){
      #pragma unroll
      for (int nf=0; nf<2; nf++){
        acc[f][nf] = __builtin_amdgcn_mfma_f32_16x16x32_bf16(a_[f][0], b0r[nf][0], acc[f][nf], 0, 0, 0);
        acc[f][nf] = __builtin_amdgcn_mfma_f32_16x16x32_bf16(a_[f][1], b0r[nf][1], acc[f][nf], 0, 0, 0);
      }
    }
    __builtin_amdgcn_s_setprio(0);
    asm volatile("s_barrier" ::: "memory");

    // ---- phase q1 ----
    #pragma unroll
    for (int nf=0; nf<2; nf++){
      b1r[nf][0] = *(const bf16x8*)&sB1[rB[nf] + colk0];
      b1r[nf][1] = *(const bf16x8*)&sB1[rB[nf] + colk1];
    }
    if (st2) STAGE8(A0p + kc2, d);
    asm volatile("s_barrier" ::: "memory");
    asm volatile("s_waitcnt lgkmcnt(0)" ::: "memory");
    __builtin_amdgcn_sched_barrier(0);
    __builtin_amdgcn_s_setprio(1);
    #pragma unroll
    for (int f=0; f<4; f++){
      #pragma unroll
      for (int nf=0; nf<2; nf++){
        acc[f][2+nf] = __builtin_amdgcn_mfma_f32_16x16x32_bf16(a_[f][0], b1r[nf][0], acc[f][2+nf], 0, 0, 0);
        acc[f][2+nf] = __builtin_amdgcn_mfma_f32_16x16x32_bf16(a_[f][1], b1r[nf][1], acc[f][2+nf], 0, 0, 0);
      }
    }
    __builtin_amdgcn_s_setprio(0);
    asm volatile("s_barrier" ::: "memory");

    // ---- phase q2 ----
    #pragma unroll
    for (int f=0; f<4; f++){
      a_[f][0] = *(const bf16x8*)&sA1[rA[f] + colk0];
      a_[f][1] = *(const bf16x8*)&sA1[rA[f] + colk1];
    }
    if (st2) STAGE8(B0p + kc2, d + 8192);
    asm volatile("s_barrier" ::: "memory");
    asm volatile("s_waitcnt lgkmcnt(0)" ::: "memory");
    __builtin_amdgcn_sched_barrier(0);
    __builtin_amdgcn_s_setprio(1);
    #pragma unroll
    for (int f=0; f<4; f++){
      #pragma unroll
      for (int nf=0; nf<2; nf++){
        acc[4+f][2+nf] = __builtin_amdgcn_mfma_f32_16x16x32_bf16(a_[f][0], b1r[nf][0], acc[4+f][2+nf], 0, 0, 0);
        acc[4+f][2+nf] = __builtin_amdgcn_mfma_f32_16x16x32_bf16(a_[f][1], b1r[nf][1], acc[4+f][2+nf], 0, 0, 0);
      }
    }
    __builtin_amdgcn_s_setprio(0);
    asm volatile("s_barrier" ::: "memory");

    // ---- phase q3 ----
    if (st2) STAGE8(B1p + kc2, d + 16384);
    __builtin_amdgcn_s_setprio(1);
    #pragma unroll
    for (int f=0; f<4; f++){
      #pragma unroll
      for (int nf=0; nf<2; nf++){
        acc[4+f][nf] = __builtin_amdgcn_mfma_f32_16x16x32_bf16(a_[f][0], b0r[nf][0], acc[4+f][nf], 0, 0, 0);
        acc[4+f][nf] = __builtin_amdgcn_mfma_f32_16x16x32_bf16(a_[f][1], b0r[nf][1], acc[4+f][nf], 0, 0, 0);
      }
    }
    __builtin_amdgcn_s_setprio(0);
    if (T+1 < NT){
      if (st2) asm volatile("s_waitcnt vmcnt(6)" ::: "memory");
      else     asm volatile("s_waitcnt vmcnt(0)" ::: "memory");
    }
    asm volatile("s_barrier" ::: "memory");
  }
  #undef STAGE8

  #pragma unroll
  for (int mh=0; mh<2; mh++){
    #pragma unroll
    for (int f=0; f<4; f++){
      #pragma unroll
      for (int nh=0; nh<2; nh++){
        #pragma unroll
        for (int nf=0; nf<2; nf++){
          #pragma unroll
          for (int jj=0; jj<4; jj++){
            int gr = m0 + mh*128 + wm*64 + f*16 + lg*4 + jj;
            int gc = n0 + nh*128 + wn*32 + nf*16 + lr;
            float v = acc[mh*4+f][nh*2+nf][jj] + bias[gc];
            if (OUT_BF16) ((u16*)Cv)[(size_t)gr*ldC + gc] = f2bf(v);
            else          ((float*)Cv)[(size_t)gr*ldC + gc] = v;
          }
        }
      }
    }
  }
}

// ---------------- pipelined GEMM: BM=128,BN=256,BK=64, 2-phase, 3-deep ----------------
template<int OUT_BF16>
__global__ __launch_bounds__(512) void gemm3_kernel(const u16* __restrict__ A, const u16* __restrict__ Bt,
                              const float* __restrict__ bias, void* __restrict__ Cv,
                              int K, int ldC, int NBM)
{
  extern __shared__ u16 lds[];   // 3 * 24576 u16 = 147456 B
  int tid = threadIdx.x;
  int lane = tid & 63;
  int wave = tid >> 6;
  int lr = lane & 15, lg = lane >> 4;
  int wm = wave >> 2, wn = wave & 3;

  int nwg = gridDim.x;
  int cpx = nwg >> 3;
  int b0 = blockIdx.x;
  int swz = (b0 & 7) * cpx + (b0 >> 3);
  int bm = swz % NBM, bn = swz / NBM;
  int m0 = bm * 128, n0 = bn * 256;

  int NT = K >> 6;

  unsigned offA[2]; int ldsA[2];
  #pragma unroll
  for (int i=0;i<2;i++){
    int c = tid + i*512;
    int row = c >> 3, blk = c & 7;
    offA[i] = (unsigned)(m0 + row)*K + (unsigned)((blk ^ (row & 7))*8);
    ldsA[i] = c*8;
  }
  unsigned offB[4]; int ldsB[4];
  #pragma unroll
  for (int i=0;i<4;i++){
    int c = tid + i*512;
    int row = c >> 3, blk = c & 7;
    offB[i] = (unsigned)(n0 + row)*K + (unsigned)((blk ^ (row & 7))*8);
    ldsB[i] = c*8;
  }

  int colk[2];
  colk[0] = ((lg)     ^ (lr & 7))*8;
  colk[1] = ((4 + lg) ^ (lr & 7))*8;
  int rA[4], rB[4];
  #pragma unroll
  for (int m=0;m<4;m++) rA[m] = (wm*64 + m*16 + lr)*64;
  #pragma unroll
  for (int n=0;n<4;n++) rB[n] = (wn*64 + n*16 + lr)*64;

  f32x4 acc[4][4] = {};

  #pragma unroll
  for (int tt=0; tt<2; ++tt){
    u16* dA = lds + tt*24576;
    u16* dB = dA + 8192;
    int k0 = tt*64;
    #pragma unroll
    for (int i=0;i<2;i++) gload_lds16(A + offA[i] + k0, dA + ldsA[i]);
    #pragma unroll
    for (int i=0;i<4;i++) gload_lds16(Bt + offB[i] + k0, dB + ldsB[i]);
  }
  asm volatile("s_waitcnt vmcnt(6)" ::: "memory");
  asm volatile("s_barrier" ::: "memory");

  int p = 0, s2 = 2;
  for (int t = 0; t < NT; ++t){
    const u16* bA = lds + p*24576;
    const u16* bB = bA + 8192;
    u16* dA = lds + s2*24576;
    u16* dB = dA + 8192;
    bool st = (t + 2) < NT;
    int k2 = (t + 2) << 6;

    bf16x8 a_[4][2], bf0[2][2];
    #pragma unroll
    for (int m=0;m<4;m++){
      a_[m][0] = *(const bf16x8*)&bA[rA[m] + colk[0]];
      a_[m][1] = *(const bf16x8*)&bA[rA[m] + colk[1]];
    }
    #pragma unroll
    for (int n=0;n<2;n++){
      bf0[n][0] = *(const bf16x8*)&bB[rB[n] + colk[0]];
      bf0[n][1] = *(const bf16x8*)&bB[rB[n] + colk[1]];
    }
    if (st){
      gload_lds16(A + offA[0] + k2, dA + ldsA[0]);
      gload_lds16(A + offA[1] + k2, dA + ldsA[1]);
      gload_lds16(Bt + offB[0] + k2, dB + ldsB[0]);
    }
    asm volatile("s_barrier" ::: "memory");
    asm volatile("s_waitcnt lgkmcnt(0)" ::: "memory");
    __builtin_amdgcn_sched_barrier(0);
    __builtin_amdgcn_s_setprio(1);
    #pragma unroll
    for (int m=0;m<4;m++){
      #pragma unroll
      for (int n=0;n<2;n++){
        acc[m][n] = __builtin_amdgcn_mfma_f32_16x16x32_bf16(a_[m][0], bf0[n][0], acc[m][n], 0, 0, 0);
        acc[m][n] = __builtin_amdgcn_mfma_f32_16x16x32_bf16(a_[m][1], bf0[n][1], acc[m][n], 0, 0, 0);
      }
    }
    __builtin_amdgcn_s_setprio(0);
    asm volatile("s_barrier" ::: "memory");

    bf16x8 bf1[2][2];
    #pragma unroll
    for (int n=0;n<2;n++){
      bf1[n][0] = *(const bf16x8*)&bB[rB[n+2] + colk[0]];
      bf1[n][1] = *(const bf16x8*)&bB[rB[n+2] + colk[1]];
    }
    if (st){
      gload_lds16(Bt + offB[1] + k2, dB + ldsB[1]);
      gload_lds16(Bt + offB[2] + k2, dB + ldsB[2]);
      gload_lds16(Bt + offB[3] + k2, dB + ldsB[3]);
    }
    asm volatile("s_barrier" ::: "memory");
    asm volatile("s_waitcnt lgkmcnt(0)" ::: "memory");
    __builtin_amdgcn_sched_barrier(0);
    __builtin_amdgcn_s_setprio(1);
    #pragma unroll
    for (int m=0;m<4;m++){
      #pragma unroll
      for (int n=0;n<2;n++){
        acc[m][n+2] = __builtin_amdgcn_mfma_f32_16x16x32_bf16(a_[m][0], bf1[n][0], acc[m][n+2], 0, 0, 0);
        acc[m][n+2] = __builtin_amdgcn_mfma_f32_16x16x32_bf16(a_[m][1], bf1[n][1], acc[m][n+2], 0, 0, 0);
      }
    }
    __builtin_amdgcn_s_setprio(0);
    if (st) asm volatile("s_waitcnt vmcnt(6)" ::: "memory");
    else    asm volatile("s_waitcnt vmcnt(0)" ::: "memory");
    asm volatile("s_barrier" ::: "memory");

    p = (p == 2) ? 0 : p + 1;
    s2 = (s2 == 2) ? 0 : s2 + 1;
  }

  #pragma unroll
  for (int m=0;m<4;m++){
    #pragma unroll
    for (int n=0;n<4;n++){
      #pragma unroll
      for (int j=0;j<4;j++){
        int gr = m0 + wm*64 + m*16 + lg*4 + j;
        int gc = n0 + wn*64 + n*16 + lr;
        float v = acc[m][n][j] + bias[gc];
        if (OUT_BF16) ((u16*)Cv)[(size_t)gr*ldC + gc] = f2bf(v);
        else          ((float*)Cv)[(size_t)gr*ldC + gc] = v;
      }
    }
  }
}

// ---------------- RoPE + relayout ----------------
__global__ __launch_bounds__(256) void rope_kernel(const u16* __restrict__ qkv, const int* __restrict__ pos,
                            u16* __restrict__ Q, u16* __restrict__ Kc, u16* __restrict__ V)
{
  int s = blockIdx.x*4 + (threadIdx.x >> 6);
  int h = blockIdx.y;
  int i = threadIdx.x & 63;
  int half = i >> 5, ii = i & 31;
  int d0 = half*64 + ii*2;
  const u16* base = qkv + (size_t)s*12288 + h*384;
  unsigned qp = *(const unsigned*)&base[d0];
  unsigned kp = *(const unsigned*)&base[128 + d0];
  unsigned vp = *(const unsigned*)&base[256 + d0];
  float qe = bf2f((u16)qp), qo = bf2f((u16)(qp >> 16));
  float ke = bf2f((u16)kp), ko = bf2f((u16)(kp >> 16));
  float pv = (float)(pos[half*SEQL + s] + 1);
  float fr = exp2f(-(float)ii * 0.4152410118609203f);  // 10000^(-ii/32)
  float ang = pv * fr;
  float sn, cs; sincosf(ang, &sn, &cs);
  const float sc = 0.1275174313f;  // (1/sqrt(128)) * log2(e), folded into Q
  float q0 = (qe*cs - qo*sn)*sc, q1 = (qe*sn + qo*cs)*sc;
  float k0 = ke*cs - ko*sn,      k1 = ke*sn + ko*cs;
  size_t ob = ((size_t)h*SEQL + s)*HDIM + d0;
  *(unsigned*)&Q[ob]  = (unsigned)f2bf(q0) | ((unsigned)f2bf(q1) << 16);
  *(unsigned*)&Kc[ob] = (unsigned)f2bf(k0) | ((unsigned)f2bf(k1) << 16);
  *(unsigned*)&V[ob]  = vp;
}

// ---------------- V -> V^T per head: [h][s][d] -> [h][d][s] ----------------
__global__ void vtrans_kernel(const u16* __restrict__ V, u16* __restrict__ Vt){
  __shared__ u16 t[32][33];
  int h = blockIdx.z;
  int d0 = blockIdx.x*32, s0 = blockIdx.y*32;
  int tx = threadIdx.x, ty = threadIdx.y;
  const u16* Vh = V + (size_t)h*SEQL*HDIM;
  u16* Vth = Vt + (size_t)h*HDIM*SEQL;
  #pragma unroll
  for (int i=0;i<4;i++)
    t[ty*4+i][tx] = Vh[(size_t)(s0+ty*4+i)*HDIM + d0 + tx];
  __syncthreads();
  #pragma unroll
  for (int i=0;i<4;i++)
    Vth[(size_t)(d0+ty*4+i)*SEQL + s0 + tx] = t[tx][ty*4+i];
}

// ---------------- causal flash attention v8 ----------------
// v6's staged double-buffered inner loop, but 64 q-rows/block (one 16-row
// strip per wave) and 1024 blocks ordered heavy-first for LPT backfill:
// id -> qt = 31 - id/32 (heaviest dispatched first), h = id%32. The 512
// heavy blocks fill all slots (2/CU); light blocks backfill as slots free,
// fixing the 53%-utilization causal imbalance of the 512-co-resident config.
// KVBLK=64, swapped QK^T, exp2 softmax, defer-max, cvt_pk P-pack,
// diagonal-only masking. LDS ~73.5KB -> 2 blocks/CU.
__global__ __launch_bounds__(256) void attn_kernel(const u16* __restrict__ Q, const u16* __restrict__ Kc,
                             const u16* __restrict__ Vt, u16* __restrict__ ctx)
{
  __shared__ u16 lK[2][64*128];
  __shared__ u16 lV[2][128*64];
  __shared__ u16 P[4*16*68];
  int id = blockIdx.x;
  int qt = 31 - (id >> 5);    // heavy blocks dispatched first
  int h  = id & 31;
  int tid = threadIdx.x;
  int lane = tid & 63;
  int wave = tid >> 6;
  int lr = lane & 15, lg = lane >> 4;
  int q0 = qt*64 + wave*16;   // this wave's strip
  int q  = q0 + lr;
  const u16* Qh = Q  + (size_t)h*SEQL*HDIM;
  const u16* Kh = Kc + (size_t)h*SEQL*HDIM;
  const u16* Vh = Vt + (size_t)h*HDIM*SEQL;
  u16* Pw = &P[wave*1088];

  bf16x8 qf[4];
  #pragma unroll
  for (int k32=0;k32<4;k32++)
    qf[k32] = *(const bf16x8*)&Qh[(size_t)(q0+lr)*HDIM + k32*32 + lg*8];

  f32x4 o[8] = {};
  float mrun = -1e30f, lrun = 0.f;

  int nt = qt + 1;   // 64-key tiles

  #define STAGE64(BUF, T0) do {                                             \
    _Pragma("unroll")                                                       \
    for (int i=0;i<4;i++){                                                  \
      int c = i*256 + tid;                                                  \
      int row = c >> 4, b = c & 15;                                         \
      int bp = b ^ (row & 7);                                               \
      gload_lds16(Kh + (size_t)((T0) + row)*HDIM + bp*8, &lK[BUF][c*8]);    \
    }                                                                       \
    _Pragma("unroll")                                                       \
    for (int i=0;i<4;i++){                                                  \
      int c = i*256 + tid;                                                  \
      int dd = c >> 3, b = c & 7;                                           \
      int bp = b ^ (dd & 7);                                                \
      gload_lds16(Vh + (size_t)dd*SEQL + (T0) + bp*8, &lV[BUF][c*8]);       \
    }                                                                       \
  } while(0)

  STAGE64(0, 0);
  __syncthreads();

  for (int t = 0; t < nt; ++t){
    int t0 = t*64;
    int cur = t & 1;
    if (t+1 < nt) STAGE64(cur^1, t0+64);   // prefetch overlaps compute

    const u16* Kt  = &lK[cur][0];
    const u16* Vtl = &lV[cur][0];

    // ---- QK^T (swapped: lane owns q-row q) ----
    f32x4 s4[4] = {};
    #pragma unroll
    for (int g=0; g<4; g++){
      int r = g*16 + lr;
      #pragma unroll
      for (int k32=0;k32<4;k32++){
        bf16x8 kf = *(const bf16x8*)&Kt[r*128 + ((((k32<<2)|lg) ^ (lr&7)))*8];
        s4[g] = __builtin_amdgcn_mfma_f32_16x16x32_bf16(kf, qf[k32], s4[g], 0, 0, 0);
      }
    }

    // ---- softmax ----
    float sv[16];
    #pragma unroll
    for (int g=0;g<4;g++){
      #pragma unroll
      for (int j=0;j<4;j++) sv[g*4+j] = s4[g][j];
    }
    if (t0 + 63 > q0){   // diagonal tile: apply causal mask
      int kb = t0 + lg*4;
      #pragma unroll
      for (int g=0;g<4;g++){
        #pragma unroll
        for (int j=0;j<4;j++)
          sv[g*4+j] = (kb + g*16 + j > q) ? -1e30f : sv[g*4+j];
      }
    }
    float mx = fmaxf(
      fmaxf(fmaxf(fmaxf(sv[0],sv[1]),fmaxf(sv[2],sv[3])),
            fmaxf(fmaxf(sv[4],sv[5]),fmaxf(sv[6],sv[7]))),
      fmaxf(fmaxf(fmaxf(sv[8],sv[9]),fmaxf(sv[10],sv[11])),
            fmaxf(fmaxf(sv[12],sv[13]),fmaxf(sv[14],sv[15]))));
    mx = fmaxf(mx, __shfl_xor(mx, 16));
    mx = fmaxf(mx, __shfl_xor(mx, 32));
    if (!__all(mx <= mrun + 11.5415603f)){
      float mnew = fmaxf(mrun, mx);
      float scl = exp2_asm(mrun - mnew);
      lrun *= scl;
      mrun = mnew;
      float sj[4];
      #pragma unroll
      for (int j=0;j<4;j++) sj[j] = __shfl(scl, lg*4 + j);
      #pragma unroll
      for (int n=0;n<8;n++){
        #pragma unroll
        for (int j=0;j<4;j++) o[n][j] *= sj[j];
      }
    }
    float pr[16];
    #pragma unroll
    for (int i=0;i<16;i++) pr[i] = exp2_asm(sv[i] - mrun);
    float sm = (((pr[0]+pr[1]) + (pr[2]+pr[3])) + ((pr[4]+pr[5]) + (pr[6]+pr[7])))
             + (((pr[8]+pr[9]) + (pr[10]+pr[11])) + ((pr[12]+pr[13]) + (pr[14]+pr[15])));
    sm += __shfl_xor(sm, 16);
    sm += __shfl_xor(sm, 32);
    lrun += sm;
    #pragma unroll
    for (int g=0;g<4;g++){
      uint2 w;
      w.x = cvtpk_bf16(pr[g*4],   pr[g*4+1]);
      w.y = cvtpk_bf16(pr[g*4+2], pr[g*4+3]);
      *(uint2*)&Pw[lr*68 + g*16 + lg*4] = w;
    }
    bf16x8 pa0 = *(const bf16x8*)&Pw[lr*68 + lg*8];
    bf16x8 pa1 = *(const bf16x8*)&Pw[lr*68 + 32 + lg*8];

    // ---- PV ----
    #pragma unroll
    for (int n=0;n<8;n++){
      int dd = n*16 + lr;
      bf16x8 v0 = *(const bf16x8*)&Vtl[dd*64 + ((lg ^ (dd&7)))*8];
      bf16x8 v1 = *(const bf16x8*)&Vtl[dd*64 + (((4|lg) ^ (dd&7)))*8];
      o[n] = __builtin_amdgcn_mfma_f32_16x16x32_bf16(pa0, v0, o[n], 0, 0, 0);
      o[n] = __builtin_amdgcn_mfma_f32_16x16x32_bf16(pa1, v1, o[n], 0, 0, 0);
    }
    __syncthreads();
  }
  #undef STAGE64

  #pragma unroll
  for (int j=0;j<4;j++){
    float lj = __shfl(lrun, lg*4 + j);
    float inv = 1.f / lj;
    int srow = q0 + lg*4 + j;
    #pragma unroll
    for (int n=0;n<8;n++)
      ctx[(size_t)srow*HIDDEN + h*HDIM + n*16 + lr] = f2bf(o[n][j]*inv);
  }
}

extern "C" void kernel_launch(void* const* d_in, const int* in_sizes, int n_in,
                              void* d_out, int out_size, void* d_ws, size_t ws_size,
                              hipStream_t stream)
{
  const float* hs   = (const float*)d_in[0];
  const int*   pos  = (const int*)d_in[1];
  const float* Wqkv = (const float*)d_in[2];
  const float* bqkv = (const float*)d_in[3];
  const float* Wd   = (const float*)d_in[4];
  const float* bd   = (const float*)d_in[5];

  const size_t o_hs  = 0;
  const size_t o_qkv = 16777216;
  const size_t o_Wtq = 67108864;
  const size_t o_Q   = 67108864;
  const size_t o_K   = 83886080;
  const size_t o_V   = 100663296;
  const size_t o_Vt  = 117440512;
  const size_t o_Wtd = 134217728;
  const size_t need  = 167772160;
  if (ws_size < need){
    fprintf(stderr, "kernel_launch: ws too small: %zu < %zu\n", ws_size, need);
    return;
  }
  char* w = (char*)d_ws;
  u16* hsb = (u16*)(w + o_hs);
  u16* qkv = (u16*)(w + o_qkv);
  u16* ctx = (u16*)(w + o_qkv);
  u16* Wtq = (u16*)(w + o_Wtq);
  u16* Qs  = (u16*)(w + o_Q);
  u16* Ks  = (u16*)(w + o_K);
  u16* Vs  = (u16*)(w + o_V);
  u16* Vts = (u16*)(w + o_Vt);
  u16* Wtd = (u16*)(w + o_Wtd);

  const size_t g8_lds = 65536*sizeof(u16);     // 131072 B
  const size_t g3_lds = 3*24576*sizeof(u16);   // 147456 B

  cast_hs_kernel<<<dim3(4096), dim3(256), 0, stream>>>(hs, hsb, SEQL*HIDDEN/8);
  wtrans_kernel<<<dim3(384,128), dim3(32,8), 0, stream>>>(Wqkv, Wtq, 12288, 0, 4096);

  // QKV GEMM split for exact CU-rounds:
  gemm8_kernel<1><<<dim3(8*32), dim3(512), g8_lds, stream>>>(
      hsb, Wtq, bqkv, (void*)qkv, HIDDEN, 12288);
  gemm3_kernel<1><<<dim3(16*16), dim3(512), g3_lds, stream>>>(
      hsb, Wtq + (size_t)8192*HIDDEN, bqkv + 8192, (void*)(qkv + 8192),
      HIDDEN, 12288, 16);

  wtrans_kernel<<<dim3(128,128), dim3(32,8), 0, stream>>>(Wd, Wtd, 4096, 0, 4096);

  rope_kernel<<<dim3(SEQL/4, NHEADS), dim3(256), 0, stream>>>(qkv, pos, Qs, Ks, Vs);
  vtrans_kernel<<<dim3(4, 64, NHEADS), dim3(32,8), 0, stream>>>(Vs, Vts);
  attn_kernel<<<dim3(1024), dim3(256), 0, stream>>>(Qs, Ks, Vts, ctx);

  // dense GEMM: [2048 x 4096] x [4096 x 4096]^T -> d_out f32 (1 exact CU-round)
  gemm3_kernel<0><<<dim3(16*16), dim3(512), g3_lds, stream>>>(
      ctx, Wtd, bd, d_out, HIDDEN, HIDDEN, 16);
}

// Round 13
// 445.135 us; speedup vs baseline: 1.3627x; 1.0134x over previous
//
#include <hip/hip_runtime.h>
#include <cstdint>
#include <cstdio>

typedef unsigned short u16;
typedef short bf16x8 __attribute__((ext_vector_type(8)));
typedef float f32x4 __attribute__((ext_vector_type(4)));
typedef unsigned short u16x8 __attribute__((ext_vector_type(8)));

#define SEQL 2048
#define NHEADS 32
#define HDIM 128
#define HIDDEN 4096

__device__ __forceinline__ u16 f2bf(float x){
  union { float f; unsigned u; } v; v.f = x;
  unsigned r = v.u + 0x7fffu + ((v.u >> 16) & 1u);
  return (u16)(r >> 16);
}
__device__ __forceinline__ float bf2f(u16 x){
  union { unsigned u; float f; } v; v.u = ((unsigned)x) << 16;
  return v.f;
}
__device__ __forceinline__ float exp2_asm(float x){
  float r; asm("v_exp_f32 %0, %1" : "=v"(r) : "v"(x)); return r;
}
__device__ __forceinline__ unsigned cvtpk_bf16(float lo, float hi){
  unsigned r; asm("v_cvt_pk_bf16_f32 %0, %1, %2" : "=v"(r) : "v"(lo), "v"(hi)); return r;
}

__device__ __forceinline__ void gload_lds16(const u16* g, u16* l){
  __builtin_amdgcn_global_load_lds((const __attribute__((address_space(1))) void*)g,
                                   (__attribute__((address_space(3))) void*)l, 16, 0, 0);
}

// ---------------- cast hidden_states f32 -> bf16 ----------------
__global__ void cast_hs_kernel(const float* __restrict__ in, u16* __restrict__ out, int n8){
  int i = blockIdx.x * blockDim.x + threadIdx.x;
  if (i >= n8) return;
  const float4* p = (const float4*)in + (size_t)i*2;
  float4 a = p[0], b = p[1];
  u16x8 o;
  o[0]=f2bf(a.x); o[1]=f2bf(a.y); o[2]=f2bf(a.z); o[3]=f2bf(a.w);
  o[4]=f2bf(b.x); o[5]=f2bf(b.y); o[6]=f2bf(b.z); o[7]=f2bf(b.w);
  *((u16x8*)out + i) = o;
}

// ---------------- wtrans64: W[K][Ntot] f32 -> Wt[n][k] bf16, 64x64 tiles ----------------
// 256 threads (64x4), 16 elems/thread. Reads 256B rows, writes 128B rows.
// LDS [64][65] f32: load lanes stride-1 (conflict-free), store lanes stride-65
// (bank-linear, conflict-free).
__global__ __launch_bounds__(256) void wtrans64_kernel(const float* __restrict__ W, u16* __restrict__ Wt,
                                int Ntot, int K){
  __shared__ float t[64][65];
  int tx = threadIdx.x & 63, ty = threadIdx.x >> 6;
  int nn = blockIdx.x*64, k0 = blockIdx.y*64;
  #pragma unroll
  for (int i=0;i<16;i++){
    int r = ty*16 + i;
    t[r][tx] = W[(size_t)(k0+r)*Ntot + nn + tx];
  }
  __syncthreads();
  #pragma unroll
  for (int i=0;i<16;i++){
    int r = ty*16 + i;
    Wt[(size_t)(nn+r)*K + k0 + tx] = f2bf(t[tx][r]);
  }
}

// ---------------- 8-phase 256x256 GEMM (refcheck-passed; exact-round grids only) ----------------
template<int OUT_BF16>
__global__ __launch_bounds__(512, 2) void gemm8_kernel(const u16* __restrict__ A, const u16* __restrict__ Bt,
                              const float* __restrict__ bias, void* __restrict__ Cv,
                              int K, int ldC)
{
  extern __shared__ u16 lds[];   // 65536 u16 = 131072 B
  int tid = threadIdx.x;
  int lane = tid & 63;
  int wave = tid >> 6;
  int lr = lane & 15, lg = lane >> 4;
  int wm = wave >> 2, wn = wave & 3;

  int nwg = gridDim.x;
  int cpx = nwg >> 3;
  int b0 = blockIdx.x;
  int swz = (b0 & 7) * cpx + (b0 >> 3);
  int bm = swz & 7, bn = swz >> 3;      // compact: 8 bm fast, bn slow
  int m0 = bm * 256, n0 = bn * 256;
  int NT = K >> 6;

  int r0 = tid >> 3;
  int cb0 = ((tid & 7) ^ (r0 & 7)) * 8;

  const u16* A0p = A  + (size_t)m0*K;
  const u16* A1p = A  + (size_t)(m0+128)*K;
  const u16* B0p = Bt + (size_t)n0*K;
  const u16* B1p = Bt + (size_t)(n0+128)*K;

  #define STAGE8(G, SLOT) do {                                        \
    gload_lds16((G) + (size_t)r0*K + cb0, lds + (SLOT) + tid*8);      \
    gload_lds16((G) + (size_t)(r0+64)*K + cb0, lds + (SLOT) + (tid+512)*8); \
  } while(0)

  int x7 = lr & 7;
  int colk0 = (lg ^ x7)*8;
  int colk1 = ((4 + lg) ^ x7)*8;
  int rA[4], rB[2];
  #pragma unroll
  for (int f=0; f<4; f++) rA[f] = (wm*64 + f*16 + lr)*64;
  #pragma unroll
  for (int nf=0; nf<2; nf++) rB[nf] = (wn*32 + nf*16 + lr)*64;

  f32x4 acc[8][4] = {};
  bf16x8 a_[4][2], b0r[2][2], b1r[2][2];

  STAGE8(A0p,      0);
  STAGE8(B0p,   8192);
  STAGE8(B1p,  16384);
  STAGE8(A1p,  24576);
  STAGE8(A0p + 64, 32768);
  STAGE8(B0p + 64, 40960);
  STAGE8(B1p + 64, 49152);
  asm volatile("s_waitcnt vmcnt(6)" ::: "memory");
  asm volatile("s_barrier" ::: "memory");

  for (int T = 0; T < NT; ++T){
    int d = (T & 1) << 15;
    int e = d ^ 32768;
    const u16* sA0 = lds + d;
    const u16* sB0 = lds + d + 8192;
    const u16* sB1 = lds + d + 16384;
    const u16* sA1 = lds + d + 24576;
    int kc  = (T+1) << 6;
    int kc2 = (T+2) << 6;
    bool st2 = (T+2) < NT;

    // ---- phase q0 ----
    #pragma unroll
    for (int f=0; f<4; f++){
      a_[f][0] = *(const bf16x8*)&sA0[rA[f] + colk0];
      a_[f][1] = *(const bf16x8*)&sA0[rA[f] + colk1];
    }
    #pragma unroll
    for (int nf=0; nf<2; nf++){
      b0r[nf][0] = *(const bf16x8*)&sB0[rB[nf] + colk0];
      b0r[nf][1] = *(const bf16x8*)&sB0[rB[nf] + colk1];
    }
    if (T+1 < NT) STAGE8(A1p + kc, e + 24576);
    asm volatile("s_barrier" ::: "memory");
    asm volatile("s_waitcnt lgkmcnt(0)" ::: "memory");
    __builtin_amdgcn_sched_barrier(0);
    __builtin_amdgcn_s_setprio(1);
    #pragma unroll
    for (int f=0; f<4; f++){
      #pragma unroll
      for (int nf=0; nf<2; nf++){
        acc[f][nf] = __builtin_amdgcn_mfma_f32_16x16x32_bf16(a_[f][0], b0r[nf][0], acc[f][nf], 0, 0, 0);
        acc[f][nf] = __builtin_amdgcn_mfma_f32_16x16x32_bf16(a_[f][1], b0r[nf][1], acc[f][nf], 0, 0, 0);
      }
    }
    __builtin_amdgcn_s_setprio(0);
    asm volatile("s_barrier" ::: "memory");

    // ---- phase q1 ----
    #pragma unroll
    for (int nf=0; nf<2; nf++){
      b1r[nf][0] = *(const bf16x8*)&sB1[rB[nf] + colk0];
      b1r[nf][1] = *(const bf16x8*)&sB1[rB[nf] + colk1];
    }
    if (st2) STAGE8(A0p + kc2, d);
    asm volatile("s_barrier" ::: "memory");
    asm volatile("s_waitcnt lgkmcnt(0)" ::: "memory");
    __builtin_amdgcn_sched_barrier(0);
    __builtin_amdgcn_s_setprio(1);
    #pragma unroll
    for (int f=0; f<4; f++){
      #pragma unroll
      for (int nf=0; nf<2; nf++){
        acc[f][2+nf] = __builtin_amdgcn_mfma_f32_16x16x32_bf16(a_[f][0], b1r[nf][0], acc[f][2+nf], 0, 0, 0);
        acc[f][2+nf] = __builtin_amdgcn_mfma_f32_16x16x32_bf16(a_[f][1], b1r[nf][1], acc[f][2+nf], 0, 0, 0);
      }
    }
    __builtin_amdgcn_s_setprio(0);
    asm volatile("s_barrier" ::: "memory");

    // ---- phase q2 ----
    #pragma unroll
    for (int f=0; f<4; f++){
      a_[f][0] = *(const bf16x8*)&sA1[rA[f] + colk0];
      a_[f][1] = *(const bf16x8*)&sA1[rA[f] + colk1];
    }
    if (st2) STAGE8(B0p + kc2, d + 8192);
    asm volatile("s_barrier" ::: "memory");
    asm volatile("s_waitcnt lgkmcnt(0)" ::: "memory");
    __builtin_amdgcn_sched_barrier(0);
    __builtin_amdgcn_s_setprio(1);
    #pragma unroll
    for (int f=0; f<4; f++){
      #pragma unroll
      for (int nf=0; nf<2; nf++){
        acc[4+f][2+nf] = __builtin_amdgcn_mfma_f32_16x16x32_bf16(a_[f][0], b1r[nf][0], acc[4+f][2+nf], 0, 0, 0);
        acc[4+f][2+nf] = __builtin_amdgcn_mfma_f32_16x16x32_bf16(a_[f][1], b1r[nf][1], acc[4+f][2+nf], 0, 0, 0);
      }
    }
    __builtin_amdgcn_s_setprio(0);
    asm volatile("s_barrier" ::: "memory");

    // ---- phase q3 ----
    if (st2) STAGE8(B1p + kc2, d + 16384);
    __builtin_amdgcn_s_setprio(1);
    #pragma unroll
    for (int f=0; f<4; f++){
      #pragma unroll
      for (int nf=0; nf<2; nf++){
        acc[4+f][nf] = __builtin_amdgcn_mfma_f32_16x16x32_bf16(a_[f][0], b0r[nf][0], acc[4+f][nf], 0, 0, 0);
        acc[4+f][nf] = __builtin_amdgcn_mfma_f32_16x16x32_bf16(a_[f][1], b0r[nf][1], acc[4+f][nf], 0, 0, 0);
      }
    }
    __builtin_amdgcn_s_setprio(0);
    if (T+1 < NT){
      if (st2) asm volatile("s_waitcnt vmcnt(6)" ::: "memory");
      else     asm volatile("s_waitcnt vmcnt(0)" ::: "memory");
    }
    asm volatile("s_barrier" ::: "memory");
  }
  #undef STAGE8

  #pragma unroll
  for (int mh=0; mh<2; mh++){
    #pragma unroll
    for (int f=0; f<4; f++){
      #pragma unroll
      for (int nh=0; nh<2; nh++){
        #pragma unroll
        for (int nf=0; nf<2; nf++){
          #pragma unroll
          for (int jj=0; jj<4; jj++){
            int gr = m0 + mh*128 + wm*64 + f*16 + lg*4 + jj;
            int gc = n0 + nh*128 + wn*32 + nf*16 + lr;
            float v = acc[mh*4+f][nh*2+nf][jj] + bias[gc];
            if (OUT_BF16) ((u16*)Cv)[(size_t)gr*ldC + gc] = f2bf(v);
            else          ((float*)Cv)[(size_t)gr*ldC + gc] = v;
          }
        }
      }
    }
  }
}

// ---------------- pipelined GEMM: BM=128,BN=256,BK=64, 2-phase, 3-deep ----------------
template<int OUT_BF16>
__global__ __launch_bounds__(512) void gemm3_kernel(const u16* __restrict__ A, const u16* __restrict__ Bt,
                              const float* __restrict__ bias, void* __restrict__ Cv,
                              int K, int ldC, int NBM)
{
  extern __shared__ u16 lds[];   // 3 * 24576 u16 = 147456 B
  int tid = threadIdx.x;
  int lane = tid & 63;
  int wave = tid >> 6;
  int lr = lane & 15, lg = lane >> 4;
  int wm = wave >> 2, wn = wave & 3;

  int nwg = gridDim.x;
  int cpx = nwg >> 3;
  int b0 = blockIdx.x;
  int swz = (b0 & 7) * cpx + (b0 >> 3);
  int bm = swz % NBM, bn = swz / NBM;
  int m0 = bm * 128, n0 = bn * 256;

  int NT = K >> 6;

  unsigned offA[2]; int ldsA[2];
  #pragma unroll
  for (int i=0;i<2;i++){
    int c = tid + i*512;
    int row = c >> 3, blk = c & 7;
    offA[i] = (unsigned)(m0 + row)*K + (unsigned)((blk ^ (row & 7))*8);
    ldsA[i] = c*8;
  }
  unsigned offB[4]; int ldsB[4];
  #pragma unroll
  for (int i=0;i<4;i++){
    int c = tid + i*512;
    int row = c >> 3, blk = c & 7;
    offB[i] = (unsigned)(n0 + row)*K + (unsigned)((blk ^ (row & 7))*8);
    ldsB[i] = c*8;
  }

  int colk[2];
  colk[0] = ((lg)     ^ (lr & 7))*8;
  colk[1] = ((4 + lg) ^ (lr & 7))*8;
  int rA[4], rB[4];
  #pragma unroll
  for (int m=0;m<4;m++) rA[m] = (wm*64 + m*16 + lr)*64;
  #pragma unroll
  for (int n=0;n<4;n++) rB[n] = (wn*64 + n*16 + lr)*64;

  f32x4 acc[4][4] = {};

  #pragma unroll
  for (int tt=0; tt<2; ++tt){
    u16* dA = lds + tt*24576;
    u16* dB = dA + 8192;
    int k0 = tt*64;
    #pragma unroll
    for (int i=0;i<2;i++) gload_lds16(A + offA[i] + k0, dA + ldsA[i]);
    #pragma unroll
    for (int i=0;i<4;i++) gload_lds16(Bt + offB[i] + k0, dB + ldsB[i]);
  }
  asm volatile("s_waitcnt vmcnt(6)" ::: "memory");
  asm volatile("s_barrier" ::: "memory");

  int p = 0, s2 = 2;
  for (int t = 0; t < NT; ++t){
    const u16* bA = lds + p*24576;
    const u16* bB = bA + 8192;
    u16* dA = lds + s2*24576;
    u16* dB = dA + 8192;
    bool st = (t + 2) < NT;
    int k2 = (t + 2) << 6;

    bf16x8 a_[4][2], bf0[2][2];
    #pragma unroll
    for (int m=0;m<4;m++){
      a_[m][0] = *(const bf16x8*)&bA[rA[m] + colk[0]];
      a_[m][1] = *(const bf16x8*)&bA[rA[m] + colk[1]];
    }
    #pragma unroll
    for (int n=0;n<2;n++){
      bf0[n][0] = *(const bf16x8*)&bB[rB[n] + colk[0]];
      bf0[n][1] = *(const bf16x8*)&bB[rB[n] + colk[1]];
    }
    if (st){
      gload_lds16(A + offA[0] + k2, dA + ldsA[0]);
      gload_lds16(A + offA[1] + k2, dA + ldsA[1]);
      gload_lds16(Bt + offB[0] + k2, dB + ldsB[0]);
    }
    asm volatile("s_barrier" ::: "memory");
    asm volatile("s_waitcnt lgkmcnt(0)" ::: "memory");
    __builtin_amdgcn_sched_barrier(0);
    __builtin_amdgcn_s_setprio(1);
    #pragma unroll
    for (int m=0;m<4;m++){
      #pragma unroll
      for (int n=0;n<2;n++){
        acc[m][n] = __builtin_amdgcn_mfma_f32_16x16x32_bf16(a_[m][0], bf0[n][0], acc[m][n], 0, 0, 0);
        acc[m][n] = __builtin_amdgcn_mfma_f32_16x16x32_bf16(a_[m][1], bf0[n][1], acc[m][n], 0, 0, 0);
      }
    }
    __builtin_amdgcn_s_setprio(0);
    asm volatile("s_barrier" ::: "memory");

    bf16x8 bf1[2][2];
    #pragma unroll
    for (int n=0;n<2;n++){
      bf1[n][0] = *(const bf16x8*)&bB[rB[n+2] + colk[0]];
      bf1[n][1] = *(const bf16x8*)&bB[rB[n+2] + colk[1]];
    }
    if (st){
      gload_lds16(Bt + offB[1] + k2, dB + ldsB[1]);
      gload_lds16(Bt + offB[2] + k2, dB + ldsB[2]);
      gload_lds16(Bt + offB[3] + k2, dB + ldsB[3]);
    }
    asm volatile("s_barrier" ::: "memory");
    asm volatile("s_waitcnt lgkmcnt(0)" ::: "memory");
    __builtin_amdgcn_sched_barrier(0);
    __builtin_amdgcn_s_setprio(1);
    #pragma unroll
    for (int m=0;m<4;m++){
      #pragma unroll
      for (int n=0;n<2;n++){
        acc[m][n+2] = __builtin_amdgcn_mfma_f32_16x16x32_bf16(a_[m][0], bf1[n][0], acc[m][n+2], 0, 0, 0);
        acc[m][n+2] = __builtin_amdgcn_mfma_f32_16x16x32_bf16(a_[m][1], bf1[n][1], acc[m][n+2], 0, 0, 0);
      }
    }
    __builtin_amdgcn_s_setprio(0);
    if (st) asm volatile("s_waitcnt vmcnt(6)" ::: "memory");
    else    asm volatile("s_waitcnt vmcnt(0)" ::: "memory");
    asm volatile("s_barrier" ::: "memory");

    p = (p == 2) ? 0 : p + 1;
    s2 = (s2 == 2) ? 0 : s2 + 1;
  }

  #pragma unroll
  for (int m=0;m<4;m++){
    #pragma unroll
    for (int n=0;n<4;n++){
      #pragma unroll
      for (int j=0;j<4;j++){
        int gr = m0 + wm*64 + m*16 + lg*4 + j;
        int gc = n0 + wn*64 + n*16 + lr;
        float v = acc[m][n][j] + bias[gc];
        if (OUT_BF16) ((u16*)Cv)[(size_t)gr*ldC + gc] = f2bf(v);
        else          ((float*)Cv)[(size_t)gr*ldC + gc] = v;
      }
    }
  }
}

// ---------------- RoPE + relayout ----------------
__global__ __launch_bounds__(256) void rope_kernel(const u16* __restrict__ qkv, const int* __restrict__ pos,
                            u16* __restrict__ Q, u16* __restrict__ Kc, u16* __restrict__ V)
{
  int s = blockIdx.x*4 + (threadIdx.x >> 6);
  int h = blockIdx.y;
  int i = threadIdx.x & 63;
  int half = i >> 5, ii = i & 31;
  int d0 = half*64 + ii*2;
  const u16* base = qkv + (size_t)s*12288 + h*384;
  unsigned qp = *(const unsigned*)&base[d0];
  unsigned kp = *(const unsigned*)&base[128 + d0];
  unsigned vp = *(const unsigned*)&base[256 + d0];
  float qe = bf2f((u16)qp), qo = bf2f((u16)(qp >> 16));
  float ke = bf2f((u16)kp), ko = bf2f((u16)(kp >> 16));
  float pv = (float)(pos[half*SEQL + s] + 1);
  float fr = exp2f(-(float)ii * 0.4152410118609203f);  // 10000^(-ii/32)
  float ang = pv * fr;
  float sn, cs; sincosf(ang, &sn, &cs);
  const float sc = 0.1275174313f;  // (1/sqrt(128)) * log2(e), folded into Q
  float q0 = (qe*cs - qo*sn)*sc, q1 = (qe*sn + qo*cs)*sc;
  float k0 = ke*cs - ko*sn,      k1 = ke*sn + ko*cs;
  size_t ob = ((size_t)h*SEQL + s)*HDIM + d0;
  *(unsigned*)&Q[ob]  = (unsigned)f2bf(q0) | ((unsigned)f2bf(q1) << 16);
  *(unsigned*)&Kc[ob] = (unsigned)f2bf(k0) | ((unsigned)f2bf(k1) << 16);
  *(unsigned*)&V[ob]  = vp;
}

// ---------------- V -> V^T per head: [h][s][d] -> [h][d][s] ----------------
__global__ void vtrans_kernel(const u16* __restrict__ V, u16* __restrict__ Vt){
  __shared__ u16 t[32][33];
  int h = blockIdx.z;
  int d0 = blockIdx.x*32, s0 = blockIdx.y*32;
  int tx = threadIdx.x, ty = threadIdx.y;
  const u16* Vh = V + (size_t)h*SEQL*HDIM;
  u16* Vth = Vt + (size_t)h*HDIM*SEQL;
  #pragma unroll
  for (int i=0;i<4;i++)
    t[ty*4+i][tx] = Vh[(size_t)(s0+ty*4+i)*HDIM + d0 + tx];
  __syncthreads();
  #pragma unroll
  for (int i=0;i<4;i++)
    Vth[(size_t)(d0+ty*4+i)*SEQL + s0 + tx] = t[tx][ty*4+i];
}

// ---------------- causal flash attention v8 (unchanged from R12) ----------------
__global__ __launch_bounds__(256) void attn_kernel(const u16* __restrict__ Q, const u16* __restrict__ Kc,
                             const u16* __restrict__ Vt, u16* __restrict__ ctx)
{
  __shared__ u16 lK[2][64*128];
  __shared__ u16 lV[2][128*64];
  __shared__ u16 P[4*16*68];
  int id = blockIdx.x;
  int qt = 31 - (id >> 5);    // heavy blocks dispatched first
  int h  = id & 31;
  int tid = threadIdx.x;
  int lane = tid & 63;
  int wave = tid >> 6;
  int lr = lane & 15, lg = lane >> 4;
  int q0 = qt*64 + wave*16;   // this wave's strip
  int q  = q0 + lr;
  const u16* Qh = Q  + (size_t)h*SEQL*HDIM;
  const u16* Kh = Kc + (size_t)h*SEQL*HDIM;
  const u16* Vh = Vt + (size_t)h*HDIM*SEQL;
  u16* Pw = &P[wave*1088];

  bf16x8 qf[4];
  #pragma unroll
  for (int k32=0;k32<4;k32++)
    qf[k32] = *(const bf16x8*)&Qh[(size_t)(q0+lr)*HDIM + k32*32 + lg*8];

  f32x4 o[8] = {};
  float mrun = -1e30f, lrun = 0.f;

  int nt = qt + 1;   // 64-key tiles

  #define STAGE64(BUF, T0) do {                                             \
    _Pragma("unroll")                                                       \
    for (int i=0;i<4;i++){                                                  \
      int c = i*256 + tid;                                                  \
      int row = c >> 4, b = c & 15;                                         \
      int bp = b ^ (row & 7);                                               \
      gload_lds16(Kh + (size_t)((T0) + row)*HDIM + bp*8, &lK[BUF][c*8]);    \
    }                                                                       \
    _Pragma("unroll")                                                       \
    for (int i=0;i<4;i++){                                                  \
      int c = i*256 + tid;                                                  \
      int dd = c >> 3, b = c & 7;                                           \
      int bp = b ^ (dd & 7);                                                \
      gload_lds16(Vh + (size_t)dd*SEQL + (T0) + bp*8, &lV[BUF][c*8]);       \
    }                                                                       \
  } while(0)

  STAGE64(0, 0);
  __syncthreads();

  for (int t = 0; t < nt; ++t){
    int t0 = t*64;
    int cur = t & 1;
    if (t+1 < nt) STAGE64(cur^1, t0+64);   // prefetch overlaps compute

    const u16* Kt  = &lK[cur][0];
    const u16* Vtl = &lV[cur][0];

    // ---- QK^T (swapped: lane owns q-row q) ----
    f32x4 s4[4] = {};
    #pragma unroll
    for (int g=0; g<4; g++){
      int r = g*16 + lr;
      #pragma unroll
      for (int k32=0;k32<4;k32++){
        bf16x8 kf = *(const bf16x8*)&Kt[r*128 + ((((k32<<2)|lg) ^ (lr&7)))*8];
        s4[g] = __builtin_amdgcn_mfma_f32_16x16x32_bf16(kf, qf[k32], s4[g], 0, 0, 0);
      }
    }

    // ---- softmax ----
    float sv[16];
    #pragma unroll
    for (int g=0;g<4;g++){
      #pragma unroll
      for (int j=0;j<4;j++) sv[g*4+j] = s4[g][j];
    }
    if (t0 + 63 > q0){   // diagonal tile: apply causal mask
      int kb = t0 + lg*4;
      #pragma unroll
      for (int g=0;g<4;g++){
        #pragma unroll
        for (int j=0;j<4;j++)
          sv[g*4+j] = (kb + g*16 + j > q) ? -1e30f : sv[g*4+j];
      }
    }
    float mx = fmaxf(
      fmaxf(fmaxf(fmaxf(sv[0],sv[1]),fmaxf(sv[2],sv[3])),
            fmaxf(fmaxf(sv[4],sv[5]),fmaxf(sv[6],sv[7]))),
      fmaxf(fmaxf(fmaxf(sv[8],sv[9]),fmaxf(sv[10],sv[11])),
            fmaxf(fmaxf(sv[12],sv[13]),fmaxf(sv[14],sv[15]))));
    mx = fmaxf(mx, __shfl_xor(mx, 16));
    mx = fmaxf(mx, __shfl_xor(mx, 32));
    if (!__all(mx <= mrun + 11.5415603f)){
      float mnew = fmaxf(mrun, mx);
      float scl = exp2_asm(mrun - mnew);
      lrun *= scl;
      mrun = mnew;
      float sj[4];
      #pragma unroll
      for (int j=0;j<4;j++) sj[j] = __shfl(scl, lg*4 + j);
      #pragma unroll
      for (int n=0;n<8;n++){
        #pragma unroll
        for (int j=0;j<4;j++) o[n][j] *= sj[j];
      }
    }
    float pr[16];
    #pragma unroll
    for (int i=0;i<16;i++) pr[i] = exp2_asm(sv[i] - mrun);
    float sm = (((pr[0]+pr[1]) + (pr[2]+pr[3])) + ((pr[4]+pr[5]) + (pr[6]+pr[7])))
             + (((pr[8]+pr[9]) + (pr[10]+pr[11])) + ((pr[12]+pr[13]) + (pr[14]+pr[15])));
    sm += __shfl_xor(sm, 16);
    sm += __shfl_xor(sm, 32);
    lrun += sm;
    #pragma unroll
    for (int g=0;g<4;g++){
      uint2 w;
      w.x = cvtpk_bf16(pr[g*4],   pr[g*4+1]);
      w.y = cvtpk_bf16(pr[g*4+2], pr[g*4+3]);
      *(uint2*)&Pw[lr*68 + g*16 + lg*4] = w;
    }
    bf16x8 pa0 = *(const bf16x8*)&Pw[lr*68 + lg*8];
    bf16x8 pa1 = *(const bf16x8*)&Pw[lr*68 + 32 + lg*8];

    // ---- PV ----
    #pragma unroll
    for (int n=0;n<8;n++){
      int dd = n*16 + lr;
      bf16x8 v0 = *(const bf16x8*)&Vtl[dd*64 + ((lg ^ (dd&7)))*8];
      bf16x8 v1 = *(const bf16x8*)&Vtl[dd*64 + (((4|lg) ^ (dd&7)))*8];
      o[n] = __builtin_amdgcn_mfma_f32_16x16x32_bf16(pa0, v0, o[n], 0, 0, 0);
      o[n] = __builtin_amdgcn_mfma_f32_16x16x32_bf16(pa1, v1, o[n], 0, 0, 0);
    }
    __syncthreads();
  }
  #undef STAGE64

  #pragma unroll
  for (int j=0;j<4;j++){
    float lj = __shfl(lrun, lg*4 + j);
    float inv = 1.f / lj;
    int srow = q0 + lg*4 + j;
    #pragma unroll
    for (int n=0;n<8;n++)
      ctx[(size_t)srow*HIDDEN + h*HDIM + n*16 + lr] = f2bf(o[n][j]*inv);
  }
}

extern "C" void kernel_launch(void* const* d_in, const int* in_sizes, int n_in,
                              void* d_out, int out_size, void* d_ws, size_t ws_size,
                              hipStream_t stream)
{
  const float* hs   = (const float*)d_in[0];
  const int*   pos  = (const int*)d_in[1];
  const float* Wqkv = (const float*)d_in[2];
  const float* bqkv = (const float*)d_in[3];
  const float* Wd   = (const float*)d_in[4];
  const float* bd   = (const float*)d_in[5];

  const size_t o_hs  = 0;
  const size_t o_qkv = 16777216;
  const size_t o_Wtq = 67108864;
  const size_t o_Q   = 67108864;
  const size_t o_K   = 83886080;
  const size_t o_V   = 100663296;
  const size_t o_Vt  = 117440512;
  const size_t o_Wtd = 134217728;
  const size_t need  = 167772160;
  if (ws_size < need){
    fprintf(stderr, "kernel_launch: ws too small: %zu < %zu\n", ws_size, need);
    return;
  }
  char* w = (char*)d_ws;
  u16* hsb = (u16*)(w + o_hs);
  u16* qkv = (u16*)(w + o_qkv);
  u16* ctx = (u16*)(w + o_qkv);
  u16* Wtq = (u16*)(w + o_Wtq);
  u16* Qs  = (u16*)(w + o_Q);
  u16* Ks  = (u16*)(w + o_K);
  u16* Vs  = (u16*)(w + o_V);
  u16* Vts = (u16*)(w + o_Vt);
  u16* Wtd = (u16*)(w + o_Wtd);

  const size_t g8_lds = 65536*sizeof(u16);     // 131072 B
  const size_t g3_lds = 3*24576*sizeof(u16);   // 147456 B

  cast_hs_kernel<<<dim3(4096), dim3(256), 0, stream>>>(hs, hsb, SEQL*HIDDEN/8);
  wtrans64_kernel<<<dim3(192,64), dim3(256), 0, stream>>>(Wqkv, Wtq, 12288, 4096);

  // QKV GEMM split for exact CU-rounds:
  gemm8_kernel<1><<<dim3(8*32), dim3(512), g8_lds, stream>>>(
      hsb, Wtq, bqkv, (void*)qkv, HIDDEN, 12288);
  gemm3_kernel<1><<<dim3(16*16), dim3(512), g3_lds, stream>>>(
      hsb, Wtq + (size_t)8192*HIDDEN, bqkv + 8192, (void*)(qkv + 8192),
      HIDDEN, 12288, 16);

  wtrans64_kernel<<<dim3(64,64), dim3(256), 0, stream>>>(Wd, Wtd, 4096, 4096);

  rope_kernel<<<dim3(SEQL/4, NHEADS), dim3(256), 0, stream>>>(qkv, pos, Qs, Ks, Vs);
  vtrans_kernel<<<dim3(4, 64, NHEADS), dim3(32,8), 0, stream>>>(Vs, Vts);
  attn_kernel<<<dim3(1024), dim3(256), 0, stream>>>(Qs, Ks, Vts, ctx);

  // dense GEMM: [2048 x 4096] x [4096 x 4096]^T -> d_out f32 (1 exact CU-round)
  gemm3_kernel<0><<<dim3(16*16), dim3(512), g3_lds, stream>>>(
      ctx, Wtd, bd, d_out, HIDDEN, HIDDEN, 16);
}

// Round 14
// 441.299 us; speedup vs baseline: 1.3746x; 1.0087x over previous
//
#include <hip/hip_runtime.h>
#include <cstdint>
#include <cstdio>

typedef unsigned short u16;
typedef short bf16x8 __attribute__((ext_vector_type(8)));
typedef float f32x4 __attribute__((ext_vector_type(4)));
typedef unsigned short u16x8 __attribute__((ext_vector_type(8)));

#define SEQL 2048
#define NHEADS 32
#define HDIM 128
#define HIDDEN 4096

__device__ __forceinline__ u16 f2bf(float x){
  union { float f; unsigned u; } v; v.f = x;
  unsigned r = v.u + 0x7fffu + ((v.u >> 16) & 1u);
  return (u16)(r >> 16);
}
__device__ __forceinline__ float bf2f(u16 x){
  union { unsigned u; float f; } v; v.u = ((unsigned)x) << 16;
  return v.f;
}
__device__ __forceinline__ float exp2_asm(float x){
  float r; asm("v_exp_f32 %0, %1" : "=v"(r) : "v"(x)); return r;
}
__device__ __forceinline__ unsigned cvtpk_bf16(float lo, float hi){
  unsigned r; asm("v_cvt_pk_bf16_f32 %0, %1, %2" : "=v"(r) : "v"(lo), "v"(hi)); return r;
}

__device__ __forceinline__ void gload_lds16(const u16* g, u16* l){
  __builtin_amdgcn_global_load_lds((const __attribute__((address_space(1))) void*)g,
                                   (__attribute__((address_space(3))) void*)l, 16, 0, 0);
}

// ---------------- cast hidden_states f32 -> bf16 ----------------
__global__ void cast_hs_kernel(const float* __restrict__ in, u16* __restrict__ out, int n8){
  int i = blockIdx.x * blockDim.x + threadIdx.x;
  if (i >= n8) return;
  const float4* p = (const float4*)in + (size_t)i*2;
  float4 a = p[0], b = p[1];
  u16x8 o;
  o[0]=f2bf(a.x); o[1]=f2bf(a.y); o[2]=f2bf(a.z); o[3]=f2bf(a.w);
  o[4]=f2bf(b.x); o[5]=f2bf(b.y); o[6]=f2bf(b.z); o[7]=f2bf(b.w);
  *((u16x8*)out + i) = o;
}

// ---------------- wtrans64: W[K][Ntot] f32 -> Wt[n][k] bf16, 64x64 tiles ----------------
__global__ __launch_bounds__(256) void wtrans64_kernel(const float* __restrict__ W, u16* __restrict__ Wt,
                                int Ntot, int K){
  __shared__ float t[64][65];
  int tx = threadIdx.x & 63, ty = threadIdx.x >> 6;
  int nn = blockIdx.x*64, k0 = blockIdx.y*64;
  #pragma unroll
  for (int i=0;i<16;i++){
    int r = ty*16 + i;
    t[r][tx] = W[(size_t)(k0+r)*Ntot + nn + tx];
  }
  __syncthreads();
  #pragma unroll
  for (int i=0;i<16;i++){
    int r = ty*16 + i;
    Wt[(size_t)(nn+r)*K + k0 + tx] = f2bf(t[tx][r]);
  }
}

// ---------------- 8-phase 256x256 GEMM (refcheck-passed; exact-round grids only) ----------------
template<int OUT_BF16>
__global__ __launch_bounds__(512, 2) void gemm8_kernel(const u16* __restrict__ A, const u16* __restrict__ Bt,
                              const float* __restrict__ bias, void* __restrict__ Cv,
                              int K, int ldC)
{
  extern __shared__ u16 lds[];   // 65536 u16 = 131072 B
  int tid = threadIdx.x;
  int lane = tid & 63;
  int wave = tid >> 6;
  int lr = lane & 15, lg = lane >> 4;
  int wm = wave >> 2, wn = wave & 3;

  int nwg = gridDim.x;
  int cpx = nwg >> 3;
  int b0 = blockIdx.x;
  int swz = (b0 & 7) * cpx + (b0 >> 3);
  int bm = swz & 7, bn = swz >> 3;      // compact: 8 bm fast, bn slow
  int m0 = bm * 256, n0 = bn * 256;
  int NT = K >> 6;

  int r0 = tid >> 3;
  int cb0 = ((tid & 7) ^ (r0 & 7)) * 8;

  const u16* A0p = A  + (size_t)m0*K;
  const u16* A1p = A  + (size_t)(m0+128)*K;
  const u16* B0p = Bt + (size_t)n0*K;
  const u16* B1p = Bt + (size_t)(n0+128)*K;

  #define STAGE8(G, SLOT) do {                                        \
    gload_lds16((G) + (size_t)r0*K + cb0, lds + (SLOT) + tid*8);      \
    gload_lds16((G) + (size_t)(r0+64)*K + cb0, lds + (SLOT) + (tid+512)*8); \
  } while(0)

  int x7 = lr & 7;
  int colk0 = (lg ^ x7)*8;
  int colk1 = ((4 + lg) ^ x7)*8;
  int rA[4], rB[2];
  #pragma unroll
  for (int f=0; f<4; f++) rA[f] = (wm*64 + f*16 + lr)*64;
  #pragma unroll
  for (int nf=0; nf<2; nf++) rB[nf] = (wn*32 + nf*16 + lr)*64;

  f32x4 acc[8][4] = {};
  bf16x8 a_[4][2], b0r[2][2], b1r[2][2];

  STAGE8(A0p,      0);
  STAGE8(B0p,   8192);
  STAGE8(B1p,  16384);
  STAGE8(A1p,  24576);
  STAGE8(A0p + 64, 32768);
  STAGE8(B0p + 64, 40960);
  STAGE8(B1p + 64, 49152);
  asm volatile("s_waitcnt vmcnt(6)" ::: "memory");
  asm volatile("s_barrier" ::: "memory");

  for (int T = 0; T < NT; ++T){
    int d = (T & 1) << 15;
    int e = d ^ 32768;
    const u16* sA0 = lds + d;
    const u16* sB0 = lds + d + 8192;
    const u16* sB1 = lds + d + 16384;
    const u16* sA1 = lds + d + 24576;
    int kc  = (T+1) << 6;
    int kc2 = (T+2) << 6;
    bool st2 = (T+2) < NT;

    // ---- phase q0 (12 ds_reads -> partial lgkm drain before barrier) ----
    #pragma unroll
    for (int f=0; f<4; f++){
      a_[f][0] = *(const bf16x8*)&sA0[rA[f] + colk0];
      a_[f][1] = *(const bf16x8*)&sA0[rA[f] + colk1];
    }
    #pragma unroll
    for (int nf=0; nf<2; nf++){
      b0r[nf][0] = *(const bf16x8*)&sB0[rB[nf] + colk0];
      b0r[nf][1] = *(const bf16x8*)&sB0[rB[nf] + colk1];
    }
    if (T+1 < NT) STAGE8(A1p + kc, e + 24576);
    asm volatile("s_waitcnt lgkmcnt(8)" ::: "memory");
    asm volatile("s_barrier" ::: "memory");
    asm volatile("s_waitcnt lgkmcnt(0)" ::: "memory");
    __builtin_amdgcn_sched_barrier(0);
    __builtin_amdgcn_s_setprio(1);
    #pragma unroll
    for (int f=0; f<4; f++){
      #pragma unroll
      for (int nf=0; nf<2; nf++){
        acc[f][nf] = __builtin_amdgcn_mfma_f32_16x16x32_bf16(a_[f][0], b0r[nf][0], acc[f][nf], 0, 0, 0);
        acc[f][nf] = __builtin_amdgcn_mfma_f32_16x16x32_bf16(a_[f][1], b0r[nf][1], acc[f][nf], 0, 0, 0);
      }
    }
    __builtin_amdgcn_s_setprio(0);
    asm volatile("s_barrier" ::: "memory");

    // ---- phase q1 ----
    #pragma unroll
    for (int nf=0; nf<2; nf++){
      b1r[nf][0] = *(const bf16x8*)&sB1[rB[nf] + colk0];
      b1r[nf][1] = *(const bf16x8*)&sB1[rB[nf] + colk1];
    }
    if (st2) STAGE8(A0p + kc2, d);
    asm volatile("s_barrier" ::: "memory");
    asm volatile("s_waitcnt lgkmcnt(0)" ::: "memory");
    __builtin_amdgcn_sched_barrier(0);
    __builtin_amdgcn_s_setprio(1);
    #pragma unroll
    for (int f=0; f<4; f++){
      #pragma unroll
      for (int nf=0; nf<2; nf++){
        acc[f][2+nf] = __builtin_amdgcn_mfma_f32_16x16x32_bf16(a_[f][0], b1r[nf][0], acc[f][2+nf], 0, 0, 0);
        acc[f][2+nf] = __builtin_amdgcn_mfma_f32_16x16x32_bf16(a_[f][1], b1r[nf][1], acc[f][2+nf], 0, 0, 0);
      }
    }
    __builtin_amdgcn_s_setprio(0);
    asm volatile("s_barrier" ::: "memory");

    // ---- phase q2 ----
    #pragma unroll
    for (int f=0; f<4; f++){
      a_[f][0] = *(const bf16x8*)&sA1[rA[f] + colk0];
      a_[f][1] = *(const bf16x8*)&sA1[rA[f] + colk1];
    }
    if (st2) STAGE8(B0p + kc2, d + 8192);
    asm volatile("s_barrier" ::: "memory");
    asm volatile("s_waitcnt lgkmcnt(0)" ::: "memory");
    __builtin_amdgcn_sched_barrier(0);
    __builtin_amdgcn_s_setprio(1);
    #pragma unroll
    for (int f=0; f<4; f++){
      #pragma unroll
      for (int nf=0; nf<2; nf++){
        acc[4+f][2+nf] = __builtin_amdgcn_mfma_f32_16x16x32_bf16(a_[f][0], b1r[nf][0], acc[4+f][2+nf], 0, 0, 0);
        acc[4+f][2+nf] = __builtin_amdgcn_mfma_f32_16x16x32_bf16(a_[f][1], b1r[nf][1], acc[4+f][2+nf], 0, 0, 0);
      }
    }
    __builtin_amdgcn_s_setprio(0);
    asm volatile("s_barrier" ::: "memory");

    // ---- phase q3 ----
    if (st2) STAGE8(B1p + kc2, d + 16384);
    __builtin_amdgcn_s_setprio(1);
    #pragma unroll
    for (int f=0; f<4; f++){
      #pragma unroll
      for (int nf=0; nf<2; nf++){
        acc[4+f][nf] = __builtin_amdgcn_mfma_f32_16x16x32_bf16(a_[f][0], b0r[nf][0], acc[4+f][nf], 0, 0, 0);
        acc[4+f][nf] = __builtin_amdgcn_mfma_f32_16x16x32_bf16(a_[f][1], b0r[nf][1], acc[4+f][nf], 0, 0, 0);
      }
    }
    __builtin_amdgcn_s_setprio(0);
    if (T+1 < NT){
      if (st2) asm volatile("s_waitcnt vmcnt(6)" ::: "memory");
      else     asm volatile("s_waitcnt vmcnt(0)" ::: "memory");
    }
    asm volatile("s_barrier" ::: "memory");
  }
  #undef STAGE8

  #pragma unroll
  for (int mh=0; mh<2; mh++){
    #pragma unroll
    for (int f=0; f<4; f++){
      #pragma unroll
      for (int nh=0; nh<2; nh++){
        #pragma unroll
        for (int nf=0; nf<2; nf++){
          #pragma unroll
          for (int jj=0; jj<4; jj++){
            int gr = m0 + mh*128 + wm*64 + f*16 + lg*4 + jj;
            int gc = n0 + nh*128 + wn*32 + nf*16 + lr;
            float v = acc[mh*4+f][nh*2+nf][jj] + bias[gc];
            if (OUT_BF16) ((u16*)Cv)[(size_t)gr*ldC + gc] = f2bf(v);
            else          ((float*)Cv)[(size_t)gr*ldC + gc] = v;
          }
        }
      }
    }
  }
}

// ---------------- pipelined GEMM: BM=128,BN=256,BK=64, 2-phase, 3-deep ----------------
template<int OUT_BF16>
__global__ __launch_bounds__(512) void gemm3_kernel(const u16* __restrict__ A, const u16* __restrict__ Bt,
                              const float* __restrict__ bias, void* __restrict__ Cv,
                              int K, int ldC, int NBM)
{
  extern __shared__ u16 lds[];   // 3 * 24576 u16 = 147456 B
  int tid = threadIdx.x;
  int lane = tid & 63;
  int wave = tid >> 6;
  int lr = lane & 15, lg = lane >> 4;
  int wm = wave >> 2, wn = wave & 3;

  int nwg = gridDim.x;
  int cpx = nwg >> 3;
  int b0 = blockIdx.x;
  int swz = (b0 & 7) * cpx + (b0 >> 3);
  int bm = swz % NBM, bn = swz / NBM;
  int m0 = bm * 128, n0 = bn * 256;

  int NT = K >> 6;

  unsigned offA[2]; int ldsA[2];
  #pragma unroll
  for (int i=0;i<2;i++){
    int c = tid + i*512;
    int row = c >> 3, blk = c & 7;
    offA[i] = (unsigned)(m0 + row)*K + (unsigned)((blk ^ (row & 7))*8);
    ldsA[i] = c*8;
  }
  unsigned offB[4]; int ldsB[4];
  #pragma unroll
  for (int i=0;i<4;i++){
    int c = tid + i*512;
    int row = c >> 3, blk = c & 7;
    offB[i] = (unsigned)(n0 + row)*K + (unsigned)((blk ^ (row & 7))*8);
    ldsB[i] = c*8;
  }

  int colk[2];
  colk[0] = ((lg)     ^ (lr & 7))*8;
  colk[1] = ((4 + lg) ^ (lr & 7))*8;
  int rA[4], rB[4];
  #pragma unroll
  for (int m=0;m<4;m++) rA[m] = (wm*64 + m*16 + lr)*64;
  #pragma unroll
  for (int n=0;n<4;n++) rB[n] = (wn*64 + n*16 + lr)*64;

  f32x4 acc[4][4] = {};

  #pragma unroll
  for (int tt=0; tt<2; ++tt){
    u16* dA = lds + tt*24576;
    u16* dB = dA + 8192;
    int k0 = tt*64;
    #pragma unroll
    for (int i=0;i<2;i++) gload_lds16(A + offA[i] + k0, dA + ldsA[i]);
    #pragma unroll
    for (int i=0;i<4;i++) gload_lds16(Bt + offB[i] + k0, dB + ldsB[i]);
  }
  asm volatile("s_waitcnt vmcnt(6)" ::: "memory");
  asm volatile("s_barrier" ::: "memory");

  int p = 0, s2 = 2;
  for (int t = 0; t < NT; ++t){
    const u16* bA = lds + p*24576;
    const u16* bB = bA + 8192;
    u16* dA = lds + s2*24576;
    u16* dB = dA + 8192;
    bool st = (t + 2) < NT;
    int k2 = (t + 2) << 6;

    bf16x8 a_[4][2], bf0[2][2];
    #pragma unroll
    for (int m=0;m<4;m++){
      a_[m][0] = *(const bf16x8*)&bA[rA[m] + colk[0]];
      a_[m][1] = *(const bf16x8*)&bA[rA[m] + colk[1]];
    }
    #pragma unroll
    for (int n=0;n<2;n++){
      bf0[n][0] = *(const bf16x8*)&bB[rB[n] + colk[0]];
      bf0[n][1] = *(const bf16x8*)&bB[rB[n] + colk[1]];
    }
    if (st){
      gload_lds16(A + offA[0] + k2, dA + ldsA[0]);
      gload_lds16(A + offA[1] + k2, dA + ldsA[1]);
      gload_lds16(Bt + offB[0] + k2, dB + ldsB[0]);
    }
    asm volatile("s_waitcnt lgkmcnt(8)" ::: "memory");
    asm volatile("s_barrier" ::: "memory");
    asm volatile("s_waitcnt lgkmcnt(0)" ::: "memory");
    __builtin_amdgcn_sched_barrier(0);
    __builtin_amdgcn_s_setprio(1);
    #pragma unroll
    for (int m=0;m<4;m++){
      #pragma unroll
      for (int n=0;n<2;n++){
        acc[m][n] = __builtin_amdgcn_mfma_f32_16x16x32_bf16(a_[m][0], bf0[n][0], acc[m][n], 0, 0, 0);
        acc[m][n] = __builtin_amdgcn_mfma_f32_16x16x32_bf16(a_[m][1], bf0[n][1], acc[m][n], 0, 0, 0);
      }
    }
    __builtin_amdgcn_s_setprio(0);
    asm volatile("s_barrier" ::: "memory");

    bf16x8 bf1[2][2];
    #pragma unroll
    for (int n=0;n<2;n++){
      bf1[n][0] = *(const bf16x8*)&bB[rB[n+2] + colk[0]];
      bf1[n][1] = *(const bf16x8*)&bB[rB[n+2] + colk[1]];
    }
    if (st){
      gload_lds16(Bt + offB[1] + k2, dB + ldsB[1]);
      gload_lds16(Bt + offB[2] + k2, dB + ldsB[2]);
      gload_lds16(Bt + offB[3] + k2, dB + ldsB[3]);
    }
    asm volatile("s_barrier" ::: "memory");
    asm volatile("s_waitcnt lgkmcnt(0)" ::: "memory");
    __builtin_amdgcn_sched_barrier(0);
    __builtin_amdgcn_s_setprio(1);
    #pragma unroll
    for (int m=0;m<4;m++){
      #pragma unroll
      for (int n=0;n<2;n++){
        acc[m][n+2] = __builtin_amdgcn_mfma_f32_16x16x32_bf16(a_[m][0], bf1[n][0], acc[m][n+2], 0, 0, 0);
        acc[m][n+2] = __builtin_amdgcn_mfma_f32_16x16x32_bf16(a_[m][1], bf1[n][1], acc[m][n+2], 0, 0, 0);
      }
    }
    __builtin_amdgcn_s_setprio(0);
    if (st) asm volatile("s_waitcnt vmcnt(6)" ::: "memory");
    else    asm volatile("s_waitcnt vmcnt(0)" ::: "memory");
    asm volatile("s_barrier" ::: "memory");

    p = (p == 2) ? 0 : p + 1;
    s2 = (s2 == 2) ? 0 : s2 + 1;
  }

  #pragma unroll
  for (int m=0;m<4;m++){
    #pragma unroll
    for (int n=0;n<4;n++){
      #pragma unroll
      for (int j=0;j<4;j++){
        int gr = m0 + wm*64 + m*16 + lg*4 + j;
        int gc = n0 + wn*64 + n*16 + lr;
        float v = acc[m][n][j] + bias[gc];
        if (OUT_BF16) ((u16*)Cv)[(size_t)gr*ldC + gc] = f2bf(v);
        else          ((float*)Cv)[(size_t)gr*ldC + gc] = v;
      }
    }
  }
}

// ---------------- RoPE + relayout ----------------
__global__ __launch_bounds__(256) void rope_kernel(const u16* __restrict__ qkv, const int* __restrict__ pos,
                            u16* __restrict__ Q, u16* __restrict__ Kc, u16* __restrict__ V)
{
  int s = blockIdx.x*4 + (threadIdx.x >> 6);
  int h = blockIdx.y;
  int i = threadIdx.x & 63;
  int half = i >> 5, ii = i & 31;
  int d0 = half*64 + ii*2;
  const u16* base = qkv + (size_t)s*12288 + h*384;
  unsigned qp = *(const unsigned*)&base[d0];
  unsigned kp = *(const unsigned*)&base[128 + d0];
  unsigned vp = *(const unsigned*)&base[256 + d0];
  float qe = bf2f((u16)qp), qo = bf2f((u16)(qp >> 16));
  float ke = bf2f((u16)kp), ko = bf2f((u16)(kp >> 16));
  float pv = (float)(pos[half*SEQL + s] + 1);
  float fr = exp2f(-(float)ii * 0.4152410118609203f);  // 10000^(-ii/32)
  float ang = pv * fr;
  float sn, cs; sincosf(ang, &sn, &cs);
  const float sc = 0.1275174313f;  // (1/sqrt(128)) * log2(e), folded into Q
  float q0 = (qe*cs - qo*sn)*sc, q1 = (qe*sn + qo*cs)*sc;
  float k0 = ke*cs - ko*sn,      k1 = ke*sn + ko*cs;
  size_t ob = ((size_t)h*SEQL + s)*HDIM + d0;
  *(unsigned*)&Q[ob]  = (unsigned)f2bf(q0) | ((unsigned)f2bf(q1) << 16);
  *(unsigned*)&Kc[ob] = (unsigned)f2bf(k0) | ((unsigned)f2bf(k1) << 16);
  *(unsigned*)&V[ob]  = vp;
}

// ---------------- vtrans64: V [h][s][d] -> Vt [h][d][s], 64x64 u16 tiles ----------------
// 256 threads, 16 elems/thread; 128B coalesced rows both directions.
// LDS [64][68] u16: store-side column reads are 2-way bank aliased (free).
__global__ __launch_bounds__(256) void vtrans64_kernel(const u16* __restrict__ V, u16* __restrict__ Vt){
  __shared__ u16 t[64][68];
  int h = blockIdx.z;
  int d0 = blockIdx.x*64, s0 = blockIdx.y*64;
  int tx = threadIdx.x & 63, ty = threadIdx.x >> 6;
  const u16* Vh = V + (size_t)h*SEQL*HDIM;
  u16* Vth = Vt + (size_t)h*HDIM*SEQL;
  #pragma unroll
  for (int i=0;i<16;i++){
    int r = ty*16 + i;
    t[r][tx] = Vh[(size_t)(s0+r)*HDIM + d0 + tx];
  }
  __syncthreads();
  #pragma unroll
  for (int i=0;i<16;i++){
    int r = ty*16 + i;
    Vth[(size_t)(d0+r)*SEQL + s0 + tx] = t[tx][r];
  }
}

// ---------------- causal flash attention v8 (unchanged from R12/R13) ----------------
__global__ __launch_bounds__(256) void attn_kernel(const u16* __restrict__ Q, const u16* __restrict__ Kc,
                             const u16* __restrict__ Vt, u16* __restrict__ ctx)
{
  __shared__ u16 lK[2][64*128];
  __shared__ u16 lV[2][128*64];
  __shared__ u16 P[4*16*68];
  int id = blockIdx.x;
  int qt = 31 - (id >> 5);    // heavy blocks dispatched first
  int h  = id & 31;
  int tid = threadIdx.x;
  int lane = tid & 63;
  int wave = tid >> 6;
  int lr = lane & 15, lg = lane >> 4;
  int q0 = qt*64 + wave*16;   // this wave's strip
  int q  = q0 + lr;
  const u16* Qh = Q  + (size_t)h*SEQL*HDIM;
  const u16* Kh = Kc + (size_t)h*SEQL*HDIM;
  const u16* Vh = Vt + (size_t)h*HDIM*SEQL;
  u16* Pw = &P[wave*1088];

  bf16x8 qf[4];
  #pragma unroll
  for (int k32=0;k32<4;k32++)
    qf[k32] = *(const bf16x8*)&Qh[(size_t)(q0+lr)*HDIM + k32*32 + lg*8];

  f32x4 o[8] = {};
  float mrun = -1e30f, lrun = 0.f;

  int nt = qt + 1;   // 64-key tiles

  #define STAGE64(BUF, T0) do {                                             \
    _Pragma("unroll")                                                       \
    for (int i=0;i<4;i++){                                                  \
      int c = i*256 + tid;                                                  \
      int row = c >> 4, b = c & 15;                                         \
      int bp = b ^ (row & 7);                                               \
      gload_lds16(Kh + (size_t)((T0) + row)*HDIM + bp*8, &lK[BUF][c*8]);    \
    }                                                                       \
    _Pragma("unroll")                                                       \
    for (int i=0;i<4;i++){                                                  \
      int c = i*256 + tid;                                                  \
      int dd = c >> 3, b = c & 7;                                           \
      int bp = b ^ (dd & 7);                                                \
      gload_lds16(Vh + (size_t)dd*SEQL + (T0) + bp*8, &lV[BUF][c*8]);       \
    }                                                                       \
  } while(0)

  STAGE64(0, 0);
  __syncthreads();

  for (int t = 0; t < nt; ++t){
    int t0 = t*64;
    int cur = t & 1;
    if (t+1 < nt) STAGE64(cur^1, t0+64);   // prefetch overlaps compute

    const u16* Kt  = &lK[cur][0];
    const u16* Vtl = &lV[cur][0];

    // ---- QK^T (swapped: lane owns q-row q) ----
    f32x4 s4[4] = {};
    #pragma unroll
    for (int g=0; g<4; g++){
      int r = g*16 + lr;
      #pragma unroll
      for (int k32=0;k32<4;k32++){
        bf16x8 kf = *(const bf16x8*)&Kt[r*128 + ((((k32<<2)|lg) ^ (lr&7)))*8];
        s4[g] = __builtin_amdgcn_mfma_f32_16x16x32_bf16(kf, qf[k32], s4[g], 0, 0, 0);
      }
    }

    // ---- softmax ----
    float sv[16];
    #pragma unroll
    for (int g=0;g<4;g++){
      #pragma unroll
      for (int j=0;j<4;j++) sv[g*4+j] = s4[g][j];
    }
    if (t0 + 63 > q0){   // diagonal tile: apply causal mask
      int kb = t0 + lg*4;
      #pragma unroll
      for (int g=0;g<4;g++){
        #pragma unroll
        for (int j=0;j<4;j++)
          sv[g*4+j] = (kb + g*16 + j > q) ? -1e30f : sv[g*4+j];
      }
    }
    float mx = fmaxf(
      fmaxf(fmaxf(fmaxf(sv[0],sv[1]),fmaxf(sv[2],sv[3])),
            fmaxf(fmaxf(sv[4],sv[5]),fmaxf(sv[6],sv[7]))),
      fmaxf(fmaxf(fmaxf(sv[8],sv[9]),fmaxf(sv[10],sv[11])),
            fmaxf(fmaxf(sv[12],sv[13]),fmaxf(sv[14],sv[15]))));
    mx = fmaxf(mx, __shfl_xor(mx, 16));
    mx = fmaxf(mx, __shfl_xor(mx, 32));
    if (!__all(mx <= mrun + 11.5415603f)){
      float mnew = fmaxf(mrun, mx);
      float scl = exp2_asm(mrun - mnew);
      lrun *= scl;
      mrun = mnew;
      float sj[4];
      #pragma unroll
      for (int j=0;j<4;j++) sj[j] = __shfl(scl, lg*4 + j);
      #pragma unroll
      for (int n=0;n<8;n++){
        #pragma unroll
        for (int j=0;j<4;j++) o[n][j] *= sj[j];
      }
    }
    float pr[16];
    #pragma unroll
    for (int i=0;i<16;i++) pr[i] = exp2_asm(sv[i] - mrun);
    float sm = (((pr[0]+pr[1]) + (pr[2]+pr[3])) + ((pr[4]+pr[5]) + (pr[6]+pr[7])))
             + (((pr[8]+pr[9]) + (pr[10]+pr[11])) + ((pr[12]+pr[13]) + (pr[14]+pr[15])));
    sm += __shfl_xor(sm, 16);
    sm += __shfl_xor(sm, 32);
    lrun += sm;
    #pragma unroll
    for (int g=0;g<4;g++){
      uint2 w;
      w.x = cvtpk_bf16(pr[g*4],   pr[g*4+1]);
      w.y = cvtpk_bf16(pr[g*4+2], pr[g*4+3]);
      *(uint2*)&Pw[lr*68 + g*16 + lg*4] = w;
    }
    bf16x8 pa0 = *(const bf16x8*)&Pw[lr*68 + lg*8];
    bf16x8 pa1 = *(const bf16x8*)&Pw[lr*68 + 32 + lg*8];

    // ---- PV ----
    #pragma unroll
    for (int n=0;n<8;n++){
      int dd = n*16 + lr;
      bf16x8 v0 = *(const bf16x8*)&Vtl[dd*64 + ((lg ^ (dd&7)))*8];
      bf16x8 v1 = *(const bf16x8*)&Vtl[dd*64 + (((4|lg) ^ (dd&7)))*8];
      o[n] = __builtin_amdgcn_mfma_f32_16x16x32_bf16(pa0, v0, o[n], 0, 0, 0);
      o[n] = __builtin_amdgcn_mfma_f32_16x16x32_bf16(pa1, v1, o[n], 0, 0, 0);
    }
    __syncthreads();
  }
  #undef STAGE64

  #pragma unroll
  for (int j=0;j<4;j++){
    float lj = __shfl(lrun, lg*4 + j);
    float inv = 1.f / lj;
    int srow = q0 + lg*4 + j;
    #pragma unroll
    for (int n=0;n<8;n++)
      ctx[(size_t)srow*HIDDEN + h*HDIM + n*16 + lr] = f2bf(o[n][j]*inv);
  }
}

extern "C" void kernel_launch(void* const* d_in, const int* in_sizes, int n_in,
                              void* d_out, int out_size, void* d_ws, size_t ws_size,
                              hipStream_t stream)
{
  const float* hs   = (const float*)d_in[0];
  const int*   pos  = (const int*)d_in[1];
  const float* Wqkv = (const float*)d_in[2];
  const float* bqkv = (const float*)d_in[3];
  const float* Wd   = (const float*)d_in[4];
  const float* bd   = (const float*)d_in[5];

  const size_t o_hs  = 0;
  const size_t o_qkv = 16777216;
  const size_t o_Wtq = 67108864;
  const size_t o_Q   = 67108864;
  const size_t o_K   = 83886080;
  const size_t o_V   = 100663296;
  const size_t o_Vt  = 117440512;
  const size_t o_Wtd = 134217728;
  const size_t need  = 167772160;
  if (ws_size < need){
    fprintf(stderr, "kernel_launch: ws too small: %zu < %zu\n", ws_size, need);
    return;
  }
  char* w = (char*)d_ws;
  u16* hsb = (u16*)(w + o_hs);
  u16* qkv = (u16*)(w + o_qkv);
  u16* ctx = (u16*)(w + o_qkv);
  u16* Wtq = (u16*)(w + o_Wtq);
  u16* Qs  = (u16*)(w + o_Q);
  u16* Ks  = (u16*)(w + o_K);
  u16* Vs  = (u16*)(w + o_V);
  u16* Vts = (u16*)(w + o_Vt);
  u16* Wtd = (u16*)(w + o_Wtd);

  const size_t g8_lds = 65536*sizeof(u16);     // 131072 B
  const size_t g3_lds = 3*24576*sizeof(u16);   // 147456 B

  cast_hs_kernel<<<dim3(4096), dim3(256), 0, stream>>>(hs, hsb, SEQL*HIDDEN/8);
  wtrans64_kernel<<<dim3(192,64), dim3(256), 0, stream>>>(Wqkv, Wtq, 12288, 4096);

  // QKV GEMM split for exact CU-rounds:
  gemm8_kernel<1><<<dim3(8*32), dim3(512), g8_lds, stream>>>(
      hsb, Wtq, bqkv, (void*)qkv, HIDDEN, 12288);
  gemm3_kernel<1><<<dim3(16*16), dim3(512), g3_lds, stream>>>(
      hsb, Wtq + (size_t)8192*HIDDEN, bqkv + 8192, (void*)(qkv + 8192),
      HIDDEN, 12288, 16);

  wtrans64_kernel<<<dim3(64,64), dim3(256), 0, stream>>>(Wd, Wtd, 4096, 4096);

  rope_kernel<<<dim3(SEQL/4, NHEADS), dim3(256), 0, stream>>>(qkv, pos, Qs, Ks, Vs);
  vtrans64_kernel<<<dim3(2, 32, NHEADS), dim3(256), 0, stream>>>(Vs, Vts);
  attn_kernel<<<dim3(1024), dim3(256), 0, stream>>>(Qs, Ks, Vts, ctx);

  // dense GEMM: [2048 x 4096] x [4096 x 4096]^T -> d_out f32 (1 exact CU-round)
  gemm3_kernel<0><<<dim3(16*16), dim3(512), g3_lds, stream>>>(
      ctx, Wtd, bd, d_out, HIDDEN, HIDDEN, 16);
}

// Round 15
// 440.448 us; speedup vs baseline: 1.3772x; 1.0019x over previous
//
#include <hip/hip_runtime.h>
#include <cstdint>
#include <cstdio>

typedef unsigned short u16;
typedef short bf16x8 __attribute__((ext_vector_type(8)));
typedef float f32x4 __attribute__((ext_vector_type(4)));
typedef unsigned short u16x8 __attribute__((ext_vector_type(8)));

#define SEQL 2048
#define NHEADS 32
#define HDIM 128
#define HIDDEN 4096

__device__ __forceinline__ u16 f2bf(float x){
  union { float f; unsigned u; } v; v.f = x;
  unsigned r = v.u + 0x7fffu + ((v.u >> 16) & 1u);
  return (u16)(r >> 16);
}
__device__ __forceinline__ float bf2f(u16 x){
  union { unsigned u; float f; } v; v.u = ((unsigned)x) << 16;
  return v.f;
}
__device__ __forceinline__ float exp2_asm(float x){
  float r; asm("v_exp_f32 %0, %1" : "=v"(r) : "v"(x)); return r;
}
__device__ __forceinline__ unsigned cvtpk_bf16(float lo, float hi){
  unsigned r; asm("v_cvt_pk_bf16_f32 %0, %1, %2" : "=v"(r) : "v"(lo), "v"(hi)); return r;
}

__device__ __forceinline__ void gload_lds16(const u16* g, u16* l){
  __builtin_amdgcn_global_load_lds((const __attribute__((address_space(1))) void*)g,
                                   (__attribute__((address_space(3))) void*)l, 16, 0, 0);
}

// ---------------- cast hidden_states f32 -> bf16 ----------------
__global__ void cast_hs_kernel(const float* __restrict__ in, u16* __restrict__ out, int n8){
  int i = blockIdx.x * blockDim.x + threadIdx.x;
  if (i >= n8) return;
  const float4* p = (const float4*)in + (size_t)i*2;
  float4 a = p[0], b = p[1];
  u16x8 o;
  o[0]=f2bf(a.x); o[1]=f2bf(a.y); o[2]=f2bf(a.z); o[3]=f2bf(a.w);
  o[4]=f2bf(b.x); o[5]=f2bf(b.y); o[6]=f2bf(b.z); o[7]=f2bf(b.w);
  *((u16x8*)out + i) = o;
}

// ---------------- wtrans64: W[K][Ntot] f32 -> Wt[n][k] bf16, 64x64 tiles ----------------
__global__ __launch_bounds__(256) void wtrans64_kernel(const float* __restrict__ W, u16* __restrict__ Wt,
                                int Ntot, int K){
  __shared__ float t[64][65];
  int tx = threadIdx.x & 63, ty = threadIdx.x >> 6;
  int nn = blockIdx.x*64, k0 = blockIdx.y*64;
  #pragma unroll
  for (int i=0;i<16;i++){
    int r = ty*16 + i;
    t[r][tx] = W[(size_t)(k0+r)*Ntot + nn + tx];
  }
  __syncthreads();
  #pragma unroll
  for (int i=0;i<16;i++){
    int r = ty*16 + i;
    Wt[(size_t)(nn+r)*K + k0 + tx] = f2bf(t[tx][r]);
  }
}

// ---------------- 8-phase 256x256 GEMM (refcheck-passed; exact-round grids only) ----------------
template<int OUT_BF16>
__global__ __launch_bounds__(512, 2) void gemm8_kernel(const u16* __restrict__ A, const u16* __restrict__ Bt,
                              const float* __restrict__ bias, void* __restrict__ Cv,
                              int K, int ldC)
{
  extern __shared__ u16 lds[];   // 65536 u16 = 131072 B
  int tid = threadIdx.x;
  int lane = tid & 63;
  int wave = tid >> 6;
  int lr = lane & 15, lg = lane >> 4;
  int wm = wave >> 2, wn = wave & 3;

  int nwg = gridDim.x;
  int cpx = nwg >> 3;
  int b0 = blockIdx.x;
  int swz = (b0 & 7) * cpx + (b0 >> 3);
  int bm = swz & 7, bn = swz >> 3;      // compact: 8 bm fast, bn slow
  int m0 = bm * 256, n0 = bn * 256;
  int NT = K >> 6;

  int r0 = tid >> 3;
  int cb0 = ((tid & 7) ^ (r0 & 7)) * 8;

  const u16* A0p = A  + (size_t)m0*K;
  const u16* A1p = A  + (size_t)(m0+128)*K;
  const u16* B0p = Bt + (size_t)n0*K;
  const u16* B1p = Bt + (size_t)(n0+128)*K;

  #define STAGE8(G, SLOT) do {                                        \
    gload_lds16((G) + (size_t)r0*K + cb0, lds + (SLOT) + tid*8);      \
    gload_lds16((G) + (size_t)(r0+64)*K + cb0, lds + (SLOT) + (tid+512)*8); \
  } while(0)

  int x7 = lr & 7;
  int colk0 = (lg ^ x7)*8;
  int colk1 = ((4 + lg) ^ x7)*8;
  int rA[4], rB[2];
  #pragma unroll
  for (int f=0; f<4; f++) rA[f] = (wm*64 + f*16 + lr)*64;
  #pragma unroll
  for (int nf=0; nf<2; nf++) rB[nf] = (wn*32 + nf*16 + lr)*64;

  f32x4 acc[8][4] = {};
  bf16x8 a_[4][2], b0r[2][2], b1r[2][2];

  STAGE8(A0p,      0);
  STAGE8(B0p,   8192);
  STAGE8(B1p,  16384);
  STAGE8(A1p,  24576);
  STAGE8(A0p + 64, 32768);
  STAGE8(B0p + 64, 40960);
  STAGE8(B1p + 64, 49152);
  asm volatile("s_waitcnt vmcnt(6)" ::: "memory");
  asm volatile("s_barrier" ::: "memory");

  for (int T = 0; T < NT; ++T){
    int d = (T & 1) << 15;
    int e = d ^ 32768;
    const u16* sA0 = lds + d;
    const u16* sB0 = lds + d + 8192;
    const u16* sB1 = lds + d + 16384;
    const u16* sA1 = lds + d + 24576;
    int kc  = (T+1) << 6;
    int kc2 = (T+2) << 6;
    bool st2 = (T+2) < NT;

    // ---- phase q0 ----
    #pragma unroll
    for (int f=0; f<4; f++){
      a_[f][0] = *(const bf16x8*)&sA0[rA[f] + colk0];
      a_[f][1] = *(const bf16x8*)&sA0[rA[f] + colk1];
    }
    #pragma unroll
    for (int nf=0; nf<2; nf++){
      b0r[nf][0] = *(const bf16x8*)&sB0[rB[nf] + colk0];
      b0r[nf][1] = *(const bf16x8*)&sB0[rB[nf] + colk1];
    }
    if (T+1 < NT) STAGE8(A1p + kc, e + 24576);
    asm volatile("s_barrier" ::: "memory");
    asm volatile("s_waitcnt lgkmcnt(0)" ::: "memory");
    __builtin_amdgcn_sched_barrier(0);
    __builtin_amdgcn_s_setprio(1);
    #pragma unroll
    for (int f=0; f<4; f++){
      #pragma unroll
      for (int nf=0; nf<2; nf++){
        acc[f][nf] = __builtin_amdgcn_mfma_f32_16x16x32_bf16(a_[f][0], b0r[nf][0], acc[f][nf], 0, 0, 0);
        acc[f][nf] = __builtin_amdgcn_mfma_f32_16x16x32_bf16(a_[f][1], b0r[nf][1], acc[f][nf], 0, 0, 0);
      }
    }
    __builtin_amdgcn_s_setprio(0);
    asm volatile("s_barrier" ::: "memory");

    // ---- phase q1 ----
    #pragma unroll
    for (int nf=0; nf<2; nf++){
      b1r[nf][0] = *(const bf16x8*)&sB1[rB[nf] + colk0];
      b1r[nf][1] = *(const bf16x8*)&sB1[rB[nf] + colk1];
    }
    if (st2) STAGE8(A0p + kc2, d);
    asm volatile("s_barrier" ::: "memory");
    asm volatile("s_waitcnt lgkmcnt(0)" ::: "memory");
    __builtin_amdgcn_sched_barrier(0);
    __builtin_amdgcn_s_setprio(1);
    #pragma unroll
    for (int f=0; f<4; f++){
      #pragma unroll
      for (int nf=0; nf<2; nf++){
        acc[f][2+nf] = __builtin_amdgcn_mfma_f32_16x16x32_bf16(a_[f][0], b1r[nf][0], acc[f][2+nf], 0, 0, 0);
        acc[f][2+nf] = __builtin_amdgcn_mfma_f32_16x16x32_bf16(a_[f][1], b1r[nf][1], acc[f][2+nf], 0, 0, 0);
      }
    }
    __builtin_amdgcn_s_setprio(0);
    asm volatile("s_barrier" ::: "memory");

    // ---- phase q2 ----
    #pragma unroll
    for (int f=0; f<4; f++){
      a_[f][0] = *(const bf16x8*)&sA1[rA[f] + colk0];
      a_[f][1] = *(const bf16x8*)&sA1[rA[f] + colk1];
    }
    if (st2) STAGE8(B0p + kc2, d + 8192);
    asm volatile("s_barrier" ::: "memory");
    asm volatile("s_waitcnt lgkmcnt(0)" ::: "memory");
    __builtin_amdgcn_sched_barrier(0);
    __builtin_amdgcn_s_setprio(1);
    #pragma unroll
    for (int f=0; f<4; f++){
      #pragma unroll
      for (int nf=0; nf<2; nf++){
        acc[4+f][2+nf] = __builtin_amdgcn_mfma_f32_16x16x32_bf16(a_[f][0], b1r[nf][0], acc[4+f][2+nf], 0, 0, 0);
        acc[4+f][2+nf] = __builtin_amdgcn_mfma_f32_16x16x32_bf16(a_[f][1], b1r[nf][1], acc[4+f][2+nf], 0, 0, 0);
      }
    }
    __builtin_amdgcn_s_setprio(0);
    asm volatile("s_barrier" ::: "memory");

    // ---- phase q3 ----
    if (st2) STAGE8(B1p + kc2, d + 16384);
    __builtin_amdgcn_s_setprio(1);
    #pragma unroll
    for (int f=0; f<4; f++){
      #pragma unroll
      for (int nf=0; nf<2; nf++){
        acc[4+f][nf] = __builtin_amdgcn_mfma_f32_16x16x32_bf16(a_[f][0], b0r[nf][0], acc[4+f][nf], 0, 0, 0);
        acc[4+f][nf] = __builtin_amdgcn_mfma_f32_16x16x32_bf16(a_[f][1], b0r[nf][1], acc[4+f][nf], 0, 0, 0);
      }
    }
    __builtin_amdgcn_s_setprio(0);
    if (T+1 < NT){
      if (st2) asm volatile("s_waitcnt vmcnt(6)" ::: "memory");
      else     asm volatile("s_waitcnt vmcnt(0)" ::: "memory");
    }
    asm volatile("s_barrier" ::: "memory");
  }
  #undef STAGE8

  #pragma unroll
  for (int mh=0; mh<2; mh++){
    #pragma unroll
    for (int f=0; f<4; f++){
      #pragma unroll
      for (int nh=0; nh<2; nh++){
        #pragma unroll
        for (int nf=0; nf<2; nf++){
          #pragma unroll
          for (int jj=0; jj<4; jj++){
            int gr = m0 + mh*128 + wm*64 + f*16 + lg*4 + jj;
            int gc = n0 + nh*128 + wn*32 + nf*16 + lr;
            float v = acc[mh*4+f][nh*2+nf][jj] + bias[gc];
            if (OUT_BF16) ((u16*)Cv)[(size_t)gr*ldC + gc] = f2bf(v);
            else          ((float*)Cv)[(size_t)gr*ldC + gc] = v;
          }
        }
      }
    }
  }
}

// ---------------- pipelined GEMM: BM=128,BN=256,BK=64, 2-phase, 3-deep ----------------
template<int OUT_BF16>
__global__ __launch_bounds__(512) void gemm3_kernel(const u16* __restrict__ A, const u16* __restrict__ Bt,
                              const float* __restrict__ bias, void* __restrict__ Cv,
                              int K, int ldC, int NBM)
{
  extern __shared__ u16 lds[];   // 3 * 24576 u16 = 147456 B
  int tid = threadIdx.x;
  int lane = tid & 63;
  int wave = tid >> 6;
  int lr = lane & 15, lg = lane >> 4;
  int wm = wave >> 2, wn = wave & 3;

  int nwg = gridDim.x;
  int cpx = nwg >> 3;
  int b0 = blockIdx.x;
  int swz = (b0 & 7) * cpx + (b0 >> 3);
  int bm = swz % NBM, bn = swz / NBM;
  int m0 = bm * 128, n0 = bn * 256;

  int NT = K >> 6;

  unsigned offA[2]; int ldsA[2];
  #pragma unroll
  for (int i=0;i<2;i++){
    int c = tid + i*512;
    int row = c >> 3, blk = c & 7;
    offA[i] = (unsigned)(m0 + row)*K + (unsigned)((blk ^ (row & 7))*8);
    ldsA[i] = c*8;
  }
  unsigned offB[4]; int ldsB[4];
  #pragma unroll
  for (int i=0;i<4;i++){
    int c = tid + i*512;
    int row = c >> 3, blk = c & 7;
    offB[i] = (unsigned)(n0 + row)*K + (unsigned)((blk ^ (row & 7))*8);
    ldsB[i] = c*8;
  }

  int colk[2];
  colk[0] = ((lg)     ^ (lr & 7))*8;
  colk[1] = ((4 + lg) ^ (lr & 7))*8;
  int rA[4], rB[4];
  #pragma unroll
  for (int m=0;m<4;m++) rA[m] = (wm*64 + m*16 + lr)*64;
  #pragma unroll
  for (int n=0;n<4;n++) rB[n] = (wn*64 + n*16 + lr)*64;

  f32x4 acc[4][4] = {};

  #pragma unroll
  for (int tt=0; tt<2; ++tt){
    u16* dA = lds + tt*24576;
    u16* dB = dA + 8192;
    int k0 = tt*64;
    #pragma unroll
    for (int i=0;i<2;i++) gload_lds16(A + offA[i] + k0, dA + ldsA[i]);
    #pragma unroll
    for (int i=0;i<4;i++) gload_lds16(Bt + offB[i] + k0, dB + ldsB[i]);
  }
  asm volatile("s_waitcnt vmcnt(6)" ::: "memory");
  asm volatile("s_barrier" ::: "memory");

  int p = 0, s2 = 2;
  for (int t = 0; t < NT; ++t){
    const u16* bA = lds + p*24576;
    const u16* bB = bA + 8192;
    u16* dA = lds + s2*24576;
    u16* dB = dA + 8192;
    bool st = (t + 2) < NT;
    int k2 = (t + 2) << 6;

    bf16x8 a_[4][2], bf0[2][2];
    #pragma unroll
    for (int m=0;m<4;m++){
      a_[m][0] = *(const bf16x8*)&bA[rA[m] + colk[0]];
      a_[m][1] = *(const bf16x8*)&bA[rA[m] + colk[1]];
    }
    #pragma unroll
    for (int n=0;n<2;n++){
      bf0[n][0] = *(const bf16x8*)&bB[rB[n] + colk[0]];
      bf0[n][1] = *(const bf16x8*)&bB[rB[n] + colk[1]];
    }
    if (st){
      gload_lds16(A + offA[0] + k2, dA + ldsA[0]);
      gload_lds16(A + offA[1] + k2, dA + ldsA[1]);
      gload_lds16(Bt + offB[0] + k2, dB + ldsB[0]);
    }
    asm volatile("s_barrier" ::: "memory");
    asm volatile("s_waitcnt lgkmcnt(0)" ::: "memory");
    __builtin_amdgcn_sched_barrier(0);
    __builtin_amdgcn_s_setprio(1);
    #pragma unroll
    for (int m=0;m<4;m++){
      #pragma unroll
      for (int n=0;n<2;n++){
        acc[m][n] = __builtin_amdgcn_mfma_f32_16x16x32_bf16(a_[m][0], bf0[n][0], acc[m][n], 0, 0, 0);
        acc[m][n] = __builtin_amdgcn_mfma_f32_16x16x32_bf16(a_[m][1], bf0[n][1], acc[m][n], 0, 0, 0);
      }
    }
    __builtin_amdgcn_s_setprio(0);
    asm volatile("s_barrier" ::: "memory");

    bf16x8 bf1[2][2];
    #pragma unroll
    for (int n=0;n<2;n++){
      bf1[n][0] = *(const bf16x8*)&bB[rB[n+2] + colk[0]];
      bf1[n][1] = *(const bf16x8*)&bB[rB[n+2] + colk[1]];
    }
    if (st){
      gload_lds16(Bt + offB[1] + k2, dB + ldsB[1]);
      gload_lds16(Bt + offB[2] + k2, dB + ldsB[2]);
      gload_lds16(Bt + offB[3] + k2, dB + ldsB[3]);
    }
    asm volatile("s_barrier" ::: "memory");
    asm volatile("s_waitcnt lgkmcnt(0)" ::: "memory");
    __builtin_amdgcn_sched_barrier(0);
    __builtin_amdgcn_s_setprio(1);
    #pragma unroll
    for (int m=0;m<4;m++){
      #pragma unroll
      for (int n=0;n<2;n++){
        acc[m][n+2] = __builtin_amdgcn_mfma_f32_16x16x32_bf16(a_[m][0], bf1[n][0], acc[m][n+2], 0, 0, 0);
        acc[m][n+2] = __builtin_amdgcn_mfma_f32_16x16x32_bf16(a_[m][1], bf1[n][1], acc[m][n+2], 0, 0, 0);
      }
    }
    __builtin_amdgcn_s_setprio(0);
    if (st) asm volatile("s_waitcnt vmcnt(6)" ::: "memory");
    else    asm volatile("s_waitcnt vmcnt(0)" ::: "memory");
    asm volatile("s_barrier" ::: "memory");

    p = (p == 2) ? 0 : p + 1;
    s2 = (s2 == 2) ? 0 : s2 + 1;
  }

  #pragma unroll
  for (int m=0;m<4;m++){
    #pragma unroll
    for (int n=0;n<4;n++){
      #pragma unroll
      for (int j=0;j<4;j++){
        int gr = m0 + wm*64 + m*16 + lg*4 + j;
        int gc = n0 + wn*64 + n*16 + lr;
        float v = acc[m][n][j] + bias[gc];
        if (OUT_BF16) ((u16*)Cv)[(size_t)gr*ldC + gc] = f2bf(v);
        else          ((float*)Cv)[(size_t)gr*ldC + gc] = v;
      }
    }
  }
}

// ---------------- RoPE + relayout (4 elems/thread, u64 I/O) ----------------
// thread handles dims d0..d0+3 (two rotation pairs) of one (s,h).
__global__ __launch_bounds__(256) void rope_kernel(const u16* __restrict__ qkv, const int* __restrict__ pos,
                            u16* __restrict__ Q, u16* __restrict__ Kc, u16* __restrict__ V)
{
  int sh = blockIdx.x*8 + (threadIdx.x >> 5);   // 8 (s,h) slices per block
  int s = sh >> 5, hh = sh & 31;                // gridDim.x = SEQL*32/8
  int i = threadIdx.x & 31;
  int half = i >> 4, ii = (i & 15)*2;           // ii = pair index base (0,2,..30)
  int d0 = half*64 + ii*2;                      // 4 dims per thread
  const u16* base = qkv + (size_t)s*12288 + hh*384;
  uint2 qp = *(const uint2*)&base[d0];
  uint2 kp = *(const uint2*)&base[128 + d0];
  uint2 vp = *(const uint2*)&base[256 + d0];
  float pv = (float)(pos[half*SEQL + s] + 1);
  float fr0 = exp2f(-(float)ii       * 0.4152410118609203f);  // 10000^(-ii/32)
  float fr1 = exp2f(-(float)(ii + 1) * 0.4152410118609203f);
  float sn0, cs0, sn1, cs1;
  sincosf(pv * fr0, &sn0, &cs0);
  sincosf(pv * fr1, &sn1, &cs1);
  const float sc = 0.1275174313f;  // (1/sqrt(128)) * log2(e), folded into Q
  float qe0 = bf2f((u16)qp.x), qo0 = bf2f((u16)(qp.x >> 16));
  float qe1 = bf2f((u16)qp.y), qo1 = bf2f((u16)(qp.y >> 16));
  float ke0 = bf2f((u16)kp.x), ko0 = bf2f((u16)(kp.x >> 16));
  float ke1 = bf2f((u16)kp.y), ko1 = bf2f((u16)(kp.y >> 16));
  uint2 qo, ko;
  qo.x = cvtpk_bf16((qe0*cs0 - qo0*sn0)*sc, (qe0*sn0 + qo0*cs0)*sc);
  qo.y = cvtpk_bf16((qe1*cs1 - qo1*sn1)*sc, (qe1*sn1 + qo1*cs1)*sc);
  ko.x = cvtpk_bf16(ke0*cs0 - ko0*sn0, ke0*sn0 + ko0*cs0);
  ko.y = cvtpk_bf16(ke1*cs1 - ko1*sn1, ke1*sn1 + ko1*cs1);
  size_t ob = ((size_t)hh*SEQL + s)*HDIM + d0;
  *(uint2*)&Q[ob]  = qo;
  *(uint2*)&Kc[ob] = ko;
  *(uint2*)&V[ob]  = vp;
}

// ---------------- vtrans64: V [h][s][d] -> Vt [h][d][s], 64x64 u16 tiles ----------------
__global__ __launch_bounds__(256) void vtrans64_kernel(const u16* __restrict__ V, u16* __restrict__ Vt){
  __shared__ u16 t[64][68];
  int h = blockIdx.z;
  int d0 = blockIdx.x*64, s0 = blockIdx.y*64;
  int tx = threadIdx.x & 63, ty = threadIdx.x >> 6;
  const u16* Vh = V + (size_t)h*SEQL*HDIM;
  u16* Vth = Vt + (size_t)h*HDIM*SEQL;
  #pragma unroll
  for (int i=0;i<16;i++){
    int r = ty*16 + i;
    t[r][tx] = Vh[(size_t)(s0+r)*HDIM + d0 + tx];
  }
  __syncthreads();
  #pragma unroll
  for (int i=0;i<16;i++){
    int r = ty*16 + i;
    Vth[(size_t)(d0+r)*SEQL + s0 + tx] = t[tx][r];
  }
}

// ---------------- causal flash attention v8 (unchanged) ----------------
__global__ __launch_bounds__(256) void attn_kernel(const u16* __restrict__ Q, const u16* __restrict__ Kc,
                             const u16* __restrict__ Vt, u16* __restrict__ ctx)
{
  __shared__ u16 lK[2][64*128];
  __shared__ u16 lV[2][128*64];
  __shared__ u16 P[4*16*68];
  int id = blockIdx.x;
  int qt = 31 - (id >> 5);    // heavy blocks dispatched first
  int h  = id & 31;
  int tid = threadIdx.x;
  int lane = tid & 63;
  int wave = tid >> 6;
  int lr = lane & 15, lg = lane >> 4;
  int q0 = qt*64 + wave*16;   // this wave's strip
  int q  = q0 + lr;
  const u16* Qh = Q  + (size_t)h*SEQL*HDIM;
  const u16* Kh = Kc + (size_t)h*SEQL*HDIM;
  const u16* Vh = Vt + (size_t)h*HDIM*SEQL;
  u16* Pw = &P[wave*1088];

  bf16x8 qf[4];
  #pragma unroll
  for (int k32=0;k32<4;k32++)
    qf[k32] = *(const bf16x8*)&Qh[(size_t)(q0+lr)*HDIM + k32*32 + lg*8];

  f32x4 o[8] = {};
  float mrun = -1e30f, lrun = 0.f;

  int nt = qt + 1;   // 64-key tiles

  #define STAGE64(BUF, T0) do {                                             \
    _Pragma("unroll")                                                       \
    for (int i=0;i<4;i++){                                                  \
      int c = i*256 + tid;                                                  \
      int row = c >> 4, b = c & 15;                                         \
      int bp = b ^ (row & 7);                                               \
      gload_lds16(Kh + (size_t)((T0) + row)*HDIM + bp*8, &lK[BUF][c*8]);    \
    }                                                                       \
    _Pragma("unroll")                                                       \
    for (int i=0;i<4;i++){                                                  \
      int c = i*256 + tid;                                                  \
      int dd = c >> 3, b = c & 7;                                           \
      int bp = b ^ (dd & 7);                                                \
      gload_lds16(Vh + (size_t)dd*SEQL + (T0) + bp*8, &lV[BUF][c*8]);       \
    }                                                                       \
  } while(0)

  STAGE64(0, 0);
  __syncthreads();

  for (int t = 0; t < nt; ++t){
    int t0 = t*64;
    int cur = t & 1;
    if (t+1 < nt) STAGE64(cur^1, t0+64);   // prefetch overlaps compute

    const u16* Kt  = &lK[cur][0];
    const u16* Vtl = &lV[cur][0];

    // ---- QK^T (swapped: lane owns q-row q) ----
    f32x4 s4[4] = {};
    #pragma unroll
    for (int g=0; g<4; g++){
      int r = g*16 + lr;
      #pragma unroll
      for (int k32=0;k32<4;k32++){
        bf16x8 kf = *(const bf16x8*)&Kt[r*128 + ((((k32<<2)|lg) ^ (lr&7)))*8];
        s4[g] = __builtin_amdgcn_mfma_f32_16x16x32_bf16(kf, qf[k32], s4[g], 0, 0, 0);
      }
    }

    // ---- softmax ----
    float sv[16];
    #pragma unroll
    for (int g=0;g<4;g++){
      #pragma unroll
      for (int j=0;j<4;j++) sv[g*4+j] = s4[g][j];
    }
    if (t0 + 63 > q0){   // diagonal tile: apply causal mask
      int kb = t0 + lg*4;
      #pragma unroll
      for (int g=0;g<4;g++){
        #pragma unroll
        for (int j=0;j<4;j++)
          sv[g*4+j] = (kb + g*16 + j > q) ? -1e30f : sv[g*4+j];
      }
    }
    float mx = fmaxf(
      fmaxf(fmaxf(fmaxf(sv[0],sv[1]),fmaxf(sv[2],sv[3])),
            fmaxf(fmaxf(sv[4],sv[5]),fmaxf(sv[6],sv[7]))),
      fmaxf(fmaxf(fmaxf(sv[8],sv[9]),fmaxf(sv[10],sv[11])),
            fmaxf(fmaxf(sv[12],sv[13]),fmaxf(sv[14],sv[15]))));
    mx = fmaxf(mx, __shfl_xor(mx, 16));
    mx = fmaxf(mx, __shfl_xor(mx, 32));
    if (!__all(mx <= mrun + 11.5415603f)){
      float mnew = fmaxf(mrun, mx);
      float scl = exp2_asm(mrun - mnew);
      lrun *= scl;
      mrun = mnew;
      float sj[4];
      #pragma unroll
      for (int j=0;j<4;j++) sj[j] = __shfl(scl, lg*4 + j);
      #pragma unroll
      for (int n=0;n<8;n++){
        #pragma unroll
        for (int j=0;j<4;j++) o[n][j] *= sj[j];
      }
    }
    float pr[16];
    #pragma unroll
    for (int i=0;i<16;i++) pr[i] = exp2_asm(sv[i] - mrun);
    float sm = (((pr[0]+pr[1]) + (pr[2]+pr[3])) + ((pr[4]+pr[5]) + (pr[6]+pr[7])))
             + (((pr[8]+pr[9]) + (pr[10]+pr[11])) + ((pr[12]+pr[13]) + (pr[14]+pr[15])));
    sm += __shfl_xor(sm, 16);
    sm += __shfl_xor(sm, 32);
    lrun += sm;
    #pragma unroll
    for (int g=0;g<4;g++){
      uint2 w;
      w.x = cvtpk_bf16(pr[g*4],   pr[g*4+1]);
      w.y = cvtpk_bf16(pr[g*4+2], pr[g*4+3]);
      *(uint2*)&Pw[lr*68 + g*16 + lg*4] = w;
    }
    bf16x8 pa0 = *(const bf16x8*)&Pw[lr*68 + lg*8];
    bf16x8 pa1 = *(const bf16x8*)&Pw[lr*68 + 32 + lg*8];

    // ---- PV ----
    #pragma unroll
    for (int n=0;n<8;n++){
      int dd = n*16 + lr;
      bf16x8 v0 = *(const bf16x8*)&Vtl[dd*64 + ((lg ^ (dd&7)))*8];
      bf16x8 v1 = *(const bf16x8*)&Vtl[dd*64 + (((4|lg) ^ (dd&7)))*8];
      o[n] = __builtin_amdgcn_mfma_f32_16x16x32_bf16(pa0, v0, o[n], 0, 0, 0);
      o[n] = __builtin_amdgcn_mfma_f32_16x16x32_bf16(pa1, v1, o[n], 0, 0, 0);
    }
    __syncthreads();
  }
  #undef STAGE64

  #pragma unroll
  for (int j=0;j<4;j++){
    float lj = __shfl(lrun, lg*4 + j);
    float inv = 1.f / lj;
    int srow = q0 + lg*4 + j;
    #pragma unroll
    for (int n=0;n<8;n++)
      ctx[(size_t)srow*HIDDEN + h*HDIM + n*16 + lr] = f2bf(o[n][j]*inv);
  }
}

extern "C" void kernel_launch(void* const* d_in, const int* in_sizes, int n_in,
                              void* d_out, int out_size, void* d_ws, size_t ws_size,
                              hipStream_t stream)
{
  const float* hs   = (const float*)d_in[0];
  const int*   pos  = (const int*)d_in[1];
  const float* Wqkv = (const float*)d_in[2];
  const float* bqkv = (const float*)d_in[3];
  const float* Wd   = (const float*)d_in[4];
  const float* bd   = (const float*)d_in[5];

  const size_t o_hs  = 0;
  const size_t o_qkv = 16777216;
  const size_t o_Wtq = 67108864;
  const size_t o_Q   = 67108864;
  const size_t o_K   = 83886080;
  const size_t o_V   = 100663296;
  const size_t o_Vt  = 117440512;
  const size_t o_Wtd = 134217728;
  const size_t need  = 167772160;
  if (ws_size < need){
    fprintf(stderr, "kernel_launch: ws too small: %zu < %zu\n", ws_size, need);
    return;
  }
  char* w = (char*)d_ws;
  u16* hsb = (u16*)(w + o_hs);
  u16* qkv = (u16*)(w + o_qkv);
  u16* ctx = (u16*)(w + o_qkv);
  u16* Wtq = (u16*)(w + o_Wtq);
  u16* Qs  = (u16*)(w + o_Q);
  u16* Ks  = (u16*)(w + o_K);
  u16* Vs  = (u16*)(w + o_V);
  u16* Vts = (u16*)(w + o_Vt);
  u16* Wtd = (u16*)(w + o_Wtd);

  const size_t g8_lds = 65536*sizeof(u16);     // 131072 B
  const size_t g3_lds = 3*24576*sizeof(u16);   // 147456 B

  cast_hs_kernel<<<dim3(4096), dim3(256), 0, stream>>>(hs, hsb, SEQL*HIDDEN/8);
  wtrans64_kernel<<<dim3(192,64), dim3(256), 0, stream>>>(Wqkv, Wtq, 12288, 4096);

  // QKV GEMM split for exact CU-rounds:
  gemm8_kernel<1><<<dim3(8*32), dim3(512), g8_lds, stream>>>(
      hsb, Wtq, bqkv, (void*)qkv, HIDDEN, 12288);
  gemm3_kernel<1><<<dim3(16*16), dim3(512), g3_lds, stream>>>(
      hsb, Wtq + (size_t)8192*HIDDEN, bqkv + 8192, (void*)(qkv + 8192),
      HIDDEN, 12288, 16);

  wtrans64_kernel<<<dim3(64,64), dim3(256), 0, stream>>>(Wd, Wtd, 4096, 4096);

  rope_kernel<<<dim3(SEQL*32/8), dim3(256), 0, stream>>>(qkv, pos, Qs, Ks, Vs);
  vtrans64_kernel<<<dim3(2, 32, NHEADS), dim3(256), 0, stream>>>(Vs, Vts);
  attn_kernel<<<dim3(1024), dim3(256), 0, stream>>>(Qs, Ks, Vts, ctx);

  // dense GEMM: [2048 x 4096] x [4096 x 4096]^T -> d_out f32 (1 exact CU-round)
  gemm3_kernel<0><<<dim3(16*16), dim3(512), g3_lds, stream>>>(
      ctx, Wtd, bd, d_out, HIDDEN, HIDDEN, 16);
}

// Round 16
// 434.975 us; speedup vs baseline: 1.3946x; 1.0126x over previous
//
#include <hip/hip_runtime.h>
#include <cstdint>
#include <cstdio>

typedef unsigned short u16;
typedef short bf16x8 __attribute__((ext_vector_type(8)));
typedef float f32x4 __attribute__((ext_vector_type(4)));
typedef unsigned short u16x8 __attribute__((ext_vector_type(8)));

#define SEQL 2048
#define NHEADS 32
#define HDIM 128
#define HIDDEN 4096

__device__ __forceinline__ u16 f2bf(float x){
  union { float f; unsigned u; } v; v.f = x;
  unsigned r = v.u + 0x7fffu + ((v.u >> 16) & 1u);
  return (u16)(r >> 16);
}
__device__ __forceinline__ float bf2f(u16 x){
  union { unsigned u; float f; } v; v.u = ((unsigned)x) << 16;
  return v.f;
}
__device__ __forceinline__ float exp2_asm(float x){
  float r; asm("v_exp_f32 %0, %1" : "=v"(r) : "v"(x)); return r;
}
__device__ __forceinline__ unsigned cvtpk_bf16(float lo, float hi){
  unsigned r; asm("v_cvt_pk_bf16_f32 %0, %1, %2" : "=v"(r) : "v"(lo), "v"(hi)); return r;
}

__device__ __forceinline__ void gload_lds16(const u16* g, u16* l){
  __builtin_amdgcn_global_load_lds((const __attribute__((address_space(1))) void*)g,
                                   (__attribute__((address_space(3))) void*)l, 16, 0, 0);
}

// ---------------- cast hidden_states f32 -> bf16 ----------------
__global__ void cast_hs_kernel(const float* __restrict__ in, u16* __restrict__ out, int n8){
  int i = blockIdx.x * blockDim.x + threadIdx.x;
  if (i >= n8) return;
  const float4* p = (const float4*)in + (size_t)i*2;
  float4 a = p[0], b = p[1];
  u16x8 o;
  o[0]=f2bf(a.x); o[1]=f2bf(a.y); o[2]=f2bf(a.z); o[3]=f2bf(a.w);
  o[4]=f2bf(b.x); o[5]=f2bf(b.y); o[6]=f2bf(b.z); o[7]=f2bf(b.w);
  *((u16x8*)out + i) = o;
}

// ---------------- wtrans64: W[K][Ntot] f32 -> Wt[n][k] bf16, 64x64 tiles ----------------
__global__ __launch_bounds__(256) void wtrans64_kernel(const float* __restrict__ W, u16* __restrict__ Wt,
                                int Ntot, int K){
  __shared__ float t[64][65];
  int tx = threadIdx.x & 63, ty = threadIdx.x >> 6;
  int nn = blockIdx.x*64, k0 = blockIdx.y*64;
  #pragma unroll
  for (int i=0;i<16;i++){
    int r = ty*16 + i;
    t[r][tx] = W[(size_t)(k0+r)*Ntot + nn + tx];
  }
  __syncthreads();
  #pragma unroll
  for (int i=0;i<16;i++){
    int r = ty*16 + i;
    Wt[(size_t)(nn+r)*K + k0 + tx] = f2bf(t[tx][r]);
  }
}

// ---------------- 8-phase 256x256 GEMM (refcheck-passed; exact-round grids only) ----------------
template<int OUT_BF16>
__global__ __launch_bounds__(512, 2) void gemm8_kernel(const u16* __restrict__ A, const u16* __restrict__ Bt,
                              const float* __restrict__ bias, void* __restrict__ Cv,
                              int K, int ldC)
{
  extern __shared__ u16 lds[];   // 65536 u16 = 131072 B
  int tid = threadIdx.x;
  int lane = tid & 63;
  int wave = tid >> 6;
  int lr = lane & 15, lg = lane >> 4;
  int wm = wave >> 2, wn = wave & 3;

  int nwg = gridDim.x;
  int cpx = nwg >> 3;
  int b0 = blockIdx.x;
  int swz = (b0 & 7) * cpx + (b0 >> 3);
  int bm = swz & 7, bn = swz >> 3;      // compact: 8 bm fast, bn slow
  int m0 = bm * 256, n0 = bn * 256;
  int NT = K >> 6;

  int r0 = tid >> 3;
  int cb0 = ((tid & 7) ^ (r0 & 7)) * 8;

  const u16* A0p = A  + (size_t)m0*K;
  const u16* A1p = A  + (size_t)(m0+128)*K;
  const u16* B0p = Bt + (size_t)n0*K;
  const u16* B1p = Bt + (size_t)(n0+128)*K;

  #define STAGE8(G, SLOT) do {                                        \
    gload_lds16((G) + (size_t)r0*K + cb0, lds + (SLOT) + tid*8);      \
    gload_lds16((G) + (size_t)(r0+64)*K + cb0, lds + (SLOT) + (tid+512)*8); \
  } while(0)

  int x7 = lr & 7;
  int colk0 = (lg ^ x7)*8;
  int colk1 = ((4 + lg) ^ x7)*8;
  int rA[4], rB[2];
  #pragma unroll
  for (int f=0; f<4; f++) rA[f] = (wm*64 + f*16 + lr)*64;
  #pragma unroll
  for (int nf=0; nf<2; nf++) rB[nf] = (wn*32 + nf*16 + lr)*64;

  f32x4 acc[8][4] = {};
  bf16x8 a_[4][2], b0r[2][2], b1r[2][2];

  STAGE8(A0p,      0);
  STAGE8(B0p,   8192);
  STAGE8(B1p,  16384);
  STAGE8(A1p,  24576);
  STAGE8(A0p + 64, 32768);
  STAGE8(B0p + 64, 40960);
  STAGE8(B1p + 64, 49152);
  asm volatile("s_waitcnt vmcnt(6)" ::: "memory");
  asm volatile("s_barrier" ::: "memory");

  for (int T = 0; T < NT; ++T){
    int d = (T & 1) << 15;
    int e = d ^ 32768;
    const u16* sA0 = lds + d;
    const u16* sB0 = lds + d + 8192;
    const u16* sB1 = lds + d + 16384;
    const u16* sA1 = lds + d + 24576;
    int kc  = (T+1) << 6;
    int kc2 = (T+2) << 6;
    bool st2 = (T+2) < NT;

    // ---- phase q0 ----
    #pragma unroll
    for (int f=0; f<4; f++){
      a_[f][0] = *(const bf16x8*)&sA0[rA[f] + colk0];
      a_[f][1] = *(const bf16x8*)&sA0[rA[f] + colk1];
    }
    #pragma unroll
    for (int nf=0; nf<2; nf++){
      b0r[nf][0] = *(const bf16x8*)&sB0[rB[nf] + colk0];
      b0r[nf][1] = *(const bf16x8*)&sB0[rB[nf] + colk1];
    }
    if (T+1 < NT) STAGE8(A1p + kc, e + 24576);
    asm volatile("s_barrier" ::: "memory");
    asm volatile("s_waitcnt lgkmcnt(0)" ::: "memory");
    __builtin_amdgcn_sched_barrier(0);
    __builtin_amdgcn_s_setprio(1);
    #pragma unroll
    for (int f=0; f<4; f++){
      #pragma unroll
      for (int nf=0; nf<2; nf++){
        acc[f][nf] = __builtin_amdgcn_mfma_f32_16x16x32_bf16(a_[f][0], b0r[nf][0], acc[f][nf], 0, 0, 0);
        acc[f][nf] = __builtin_amdgcn_mfma_f32_16x16x32_bf16(a_[f][1], b0r[nf][1], acc[f][nf], 0, 0, 0);
      }
    }
    __builtin_amdgcn_s_setprio(0);
    asm volatile("s_barrier" ::: "memory");

    // ---- phase q1 ----
    #pragma unroll
    for (int nf=0; nf<2; nf++){
      b1r[nf][0] = *(const bf16x8*)&sB1[rB[nf] + colk0];
      b1r[nf][1] = *(const bf16x8*)&sB1[rB[nf] + colk1];
    }
    if (st2) STAGE8(A0p + kc2, d);
    asm volatile("s_barrier" ::: "memory");
    asm volatile("s_waitcnt lgkmcnt(0)" ::: "memory");
    __builtin_amdgcn_sched_barrier(0);
    __builtin_amdgcn_s_setprio(1);
    #pragma unroll
    for (int f=0; f<4; f++){
      #pragma unroll
      for (int nf=0; nf<2; nf++){
        acc[f][2+nf] = __builtin_amdgcn_mfma_f32_16x16x32_bf16(a_[f][0], b1r[nf][0], acc[f][2+nf], 0, 0, 0);
        acc[f][2+nf] = __builtin_amdgcn_mfma_f32_16x16x32_bf16(a_[f][1], b1r[nf][1], acc[f][2+nf], 0, 0, 0);
      }
    }
    __builtin_amdgcn_s_setprio(0);
    asm volatile("s_barrier" ::: "memory");

    // ---- phase q2 ----
    #pragma unroll
    for (int f=0; f<4; f++){
      a_[f][0] = *(const bf16x8*)&sA1[rA[f] + colk0];
      a_[f][1] = *(const bf16x8*)&sA1[rA[f] + colk1];
    }
    if (st2) STAGE8(B0p + kc2, d + 8192);
    asm volatile("s_barrier" ::: "memory");
    asm volatile("s_waitcnt lgkmcnt(0)" ::: "memory");
    __builtin_amdgcn_sched_barrier(0);
    __builtin_amdgcn_s_setprio(1);
    #pragma unroll
    for (int f=0; f<4; f++){
      #pragma unroll
      for (int nf=0; nf<2; nf++){
        acc[4+f][2+nf] = __builtin_amdgcn_mfma_f32_16x16x32_bf16(a_[f][0], b1r[nf][0], acc[4+f][2+nf], 0, 0, 0);
        acc[4+f][2+nf] = __builtin_amdgcn_mfma_f32_16x16x32_bf16(a_[f][1], b1r[nf][1], acc[4+f][2+nf], 0, 0, 0);
      }
    }
    __builtin_amdgcn_s_setprio(0);
    asm volatile("s_barrier" ::: "memory");

    // ---- phase q3 ----
    if (st2) STAGE8(B1p + kc2, d + 16384);
    __builtin_amdgcn_s_setprio(1);
    #pragma unroll
    for (int f=0; f<4; f++){
      #pragma unroll
      for (int nf=0; nf<2; nf++){
        acc[4+f][nf] = __builtin_amdgcn_mfma_f32_16x16x32_bf16(a_[f][0], b0r[nf][0], acc[4+f][nf], 0, 0, 0);
        acc[4+f][nf] = __builtin_amdgcn_mfma_f32_16x16x32_bf16(a_[f][1], b0r[nf][1], acc[4+f][nf], 0, 0, 0);
      }
    }
    __builtin_amdgcn_s_setprio(0);
    if (T+1 < NT){
      if (st2) asm volatile("s_waitcnt vmcnt(6)" ::: "memory");
      else     asm volatile("s_waitcnt vmcnt(0)" ::: "memory");
    }
    asm volatile("s_barrier" ::: "memory");
  }
  #undef STAGE8

  #pragma unroll
  for (int mh=0; mh<2; mh++){
    #pragma unroll
    for (int f=0; f<4; f++){
      #pragma unroll
      for (int nh=0; nh<2; nh++){
        #pragma unroll
        for (int nf=0; nf<2; nf++){
          #pragma unroll
          for (int jj=0; jj<4; jj++){
            int gr = m0 + mh*128 + wm*64 + f*16 + lg*4 + jj;
            int gc = n0 + nh*128 + wn*32 + nf*16 + lr;
            float v = acc[mh*4+f][nh*2+nf][jj] + bias[gc];
            if (OUT_BF16) ((u16*)Cv)[(size_t)gr*ldC + gc] = f2bf(v);
            else          ((float*)Cv)[(size_t)gr*ldC + gc] = v;
          }
        }
      }
    }
  }
}

// ---------------- pipelined GEMM: BM=128,BN=256,BK=64, 2-phase, 3-deep ----------------
template<int OUT_BF16>
__global__ __launch_bounds__(512) void gemm3_kernel(const u16* __restrict__ A, const u16* __restrict__ Bt,
                              const float* __restrict__ bias, void* __restrict__ Cv,
                              int K, int ldC, int NBM)
{
  extern __shared__ u16 lds[];   // 3 * 24576 u16 = 147456 B
  int tid = threadIdx.x;
  int lane = tid & 63;
  int wave = tid >> 6;
  int lr = lane & 15, lg = lane >> 4;
  int wm = wave >> 2, wn = wave & 3;

  int nwg = gridDim.x;
  int cpx = nwg >> 3;
  int b0 = blockIdx.x;
  int swz = (b0 & 7) * cpx + (b0 >> 3);
  int bm = swz % NBM, bn = swz / NBM;
  int m0 = bm * 128, n0 = bn * 256;

  int NT = K >> 6;

  unsigned offA[2]; int ldsA[2];
  #pragma unroll
  for (int i=0;i<2;i++){
    int c = tid + i*512;
    int row = c >> 3, blk = c & 7;
    offA[i] = (unsigned)(m0 + row)*K + (unsigned)((blk ^ (row & 7))*8);
    ldsA[i] = c*8;
  }
  unsigned offB[4]; int ldsB[4];
  #pragma unroll
  for (int i=0;i<4;i++){
    int c = tid + i*512;
    int row = c >> 3, blk = c & 7;
    offB[i] = (unsigned)(n0 + row)*K + (unsigned)((blk ^ (row & 7))*8);
    ldsB[i] = c*8;
  }

  int colk[2];
  colk[0] = ((lg)     ^ (lr & 7))*8;
  colk[1] = ((4 + lg) ^ (lr & 7))*8;
  int rA[4], rB[4];
  #pragma unroll
  for (int m=0;m<4;m++) rA[m] = (wm*64 + m*16 + lr)*64;
  #pragma unroll
  for (int n=0;n<4;n++) rB[n] = (wn*64 + n*16 + lr)*64;

  f32x4 acc[4][4] = {};

  #pragma unroll
  for (int tt=0; tt<2; ++tt){
    u16* dA = lds + tt*24576;
    u16* dB = dA + 8192;
    int k0 = tt*64;
    #pragma unroll
    for (int i=0;i<2;i++) gload_lds16(A + offA[i] + k0, dA + ldsA[i]);
    #pragma unroll
    for (int i=0;i<4;i++) gload_lds16(Bt + offB[i] + k0, dB + ldsB[i]);
  }
  asm volatile("s_waitcnt vmcnt(6)" ::: "memory");
  asm volatile("s_barrier" ::: "memory");

  int p = 0, s2 = 2;
  for (int t = 0; t < NT; ++t){
    const u16* bA = lds + p*24576;
    const u16* bB = bA + 8192;
    u16* dA = lds + s2*24576;
    u16* dB = dA + 8192;
    bool st = (t + 2) < NT;
    int k2 = (t + 2) << 6;

    bf16x8 a_[4][2], bf0[2][2];
    #pragma unroll
    for (int m=0;m<4;m++){
      a_[m][0] = *(const bf16x8*)&bA[rA[m] + colk[0]];
      a_[m][1] = *(const bf16x8*)&bA[rA[m] + colk[1]];
    }
    #pragma unroll
    for (int n=0;n<2;n++){
      bf0[n][0] = *(const bf16x8*)&bB[rB[n] + colk[0]];
      bf0[n][1] = *(const bf16x8*)&bB[rB[n] + colk[1]];
    }
    if (st){
      gload_lds16(A + offA[0] + k2, dA + ldsA[0]);
      gload_lds16(A + offA[1] + k2, dA + ldsA[1]);
      gload_lds16(Bt + offB[0] + k2, dB + ldsB[0]);
    }
    asm volatile("s_barrier" ::: "memory");
    asm volatile("s_waitcnt lgkmcnt(0)" ::: "memory");
    __builtin_amdgcn_sched_barrier(0);
    __builtin_amdgcn_s_setprio(1);
    #pragma unroll
    for (int m=0;m<4;m++){
      #pragma unroll
      for (int n=0;n<2;n++){
        acc[m][n] = __builtin_amdgcn_mfma_f32_16x16x32_bf16(a_[m][0], bf0[n][0], acc[m][n], 0, 0, 0);
        acc[m][n] = __builtin_amdgcn_mfma_f32_16x16x32_bf16(a_[m][1], bf0[n][1], acc[m][n], 0, 0, 0);
      }
    }
    __builtin_amdgcn_s_setprio(0);
    asm volatile("s_barrier" ::: "memory");

    bf16x8 bf1[2][2];
    #pragma unroll
    for (int n=0;n<2;n++){
      bf1[n][0] = *(const bf16x8*)&bB[rB[n+2] + colk[0]];
      bf1[n][1] = *(const bf16x8*)&bB[rB[n+2] + colk[1]];
    }
    if (st){
      gload_lds16(Bt + offB[1] + k2, dB + ldsB[1]);
      gload_lds16(Bt + offB[2] + k2, dB + ldsB[2]);
      gload_lds16(Bt + offB[3] + k2, dB + ldsB[3]);
    }
    asm volatile("s_barrier" ::: "memory");
    asm volatile("s_waitcnt lgkmcnt(0)" ::: "memory");
    __builtin_amdgcn_sched_barrier(0);
    __builtin_amdgcn_s_setprio(1);
    #pragma unroll
    for (int m=0;m<4;m++){
      #pragma unroll
      for (int n=0;n<2;n++){
        acc[m][n+2] = __builtin_amdgcn_mfma_f32_16x16x32_bf16(a_[m][0], bf1[n][0], acc[m][n+2], 0, 0, 0);
        acc[m][n+2] = __builtin_amdgcn_mfma_f32_16x16x32_bf16(a_[m][1], bf1[n][1], acc[m][n+2], 0, 0, 0);
      }
    }
    __builtin_amdgcn_s_setprio(0);
    if (st) asm volatile("s_waitcnt vmcnt(6)" ::: "memory");
    else    asm volatile("s_waitcnt vmcnt(0)" ::: "memory");
    asm volatile("s_barrier" ::: "memory");

    p = (p == 2) ? 0 : p + 1;
    s2 = (s2 == 2) ? 0 : s2 + 1;
  }

  #pragma unroll
  for (int m=0;m<4;m++){
    #pragma unroll
    for (int n=0;n<4;n++){
      #pragma unroll
      for (int j=0;j<4;j++){
        int gr = m0 + wm*64 + m*16 + lg*4 + j;
        int gc = n0 + wn*64 + n*16 + lr;
        float v = acc[m][n][j] + bias[gc];
        if (OUT_BF16) ((u16*)Cv)[(size_t)gr*ldC + gc] = f2bf(v);
        else          ((float*)Cv)[(size_t)gr*ldC + gc] = v;
      }
    }
  }
}

// ---------------- rope2: RoPE + relayout + fused V-transpose ----------------
// Block = (64-row s-tile, head). Phase A: rope math (identical to before),
// Q/K written direct (coalesced as before), V slice parked in LDS.
// Phase B: V written out transposed in 128B coalesced rows.
// Eliminates the separate vtrans kernel + V's HBM round-trip.
__global__ __launch_bounds__(256) void rope2_kernel(const u16* __restrict__ qkv, const int* __restrict__ pos,
                             u16* __restrict__ Q, u16* __restrict__ Kc, u16* __restrict__ Vt)
{
  __shared__ u16 tv[64][132];
  int s0 = blockIdx.x*64;
  int hh = blockIdx.y;
  int t = threadIdx.x;
  const float sc = 0.1275174313f;  // (1/sqrt(128)) * log2(e), folded into Q

  #pragma unroll
  for (int it=0; it<8; ++it){
    int flat = it*256 + t;          // 0..2047
    int s = flat >> 5;              // 0..63
    int slot = flat & 31;
    int half = slot >> 4, ii = (slot & 15)*2;
    int d0 = half*64 + ii*2;        // 4 dims per thread
    const u16* base = qkv + (size_t)(s0+s)*12288 + hh*384;
    uint2 qp = *(const uint2*)&base[d0];
    uint2 kp = *(const uint2*)&base[128 + d0];
    uint2 vp = *(const uint2*)&base[256 + d0];
    float pv = (float)(pos[half*SEQL + s0 + s] + 1);
    float fr0 = exp2f(-(float)ii       * 0.4152410118609203f);  // 10000^(-ii/32)
    float fr1 = exp2f(-(float)(ii + 1) * 0.4152410118609203f);
    float sn0, cs0, sn1, cs1;
    sincosf(pv * fr0, &sn0, &cs0);
    sincosf(pv * fr1, &sn1, &cs1);
    float qe0 = bf2f((u16)qp.x), qo0 = bf2f((u16)(qp.x >> 16));
    float qe1 = bf2f((u16)qp.y), qo1 = bf2f((u16)(qp.y >> 16));
    float ke0 = bf2f((u16)kp.x), ko0 = bf2f((u16)(kp.x >> 16));
    float ke1 = bf2f((u16)kp.y), ko1 = bf2f((u16)(kp.y >> 16));
    uint2 qo, ko;
    qo.x = cvtpk_bf16((qe0*cs0 - qo0*sn0)*sc, (qe0*sn0 + qo0*cs0)*sc);
    qo.y = cvtpk_bf16((qe1*cs1 - qo1*sn1)*sc, (qe1*sn1 + qo1*cs1)*sc);
    ko.x = cvtpk_bf16(ke0*cs0 - ko0*sn0, ke0*sn0 + ko0*cs0);
    ko.y = cvtpk_bf16(ke1*cs1 - ko1*sn1, ke1*sn1 + ko1*cs1);
    size_t ob = ((size_t)hh*SEQL + s0 + s)*HDIM + d0;
    *(uint2*)&Q[ob]  = qo;
    *(uint2*)&Kc[ob] = ko;
    *(uint2*)&tv[s][d0] = vp;
  }
  __syncthreads();
  int tx = t & 63, ty = t >> 6;
  u16* Vth = Vt + (size_t)hh*HDIM*SEQL;
  #pragma unroll
  for (int k=0;k<32;k++){
    int d = ty*32 + k;
    Vth[(size_t)d*SEQL + s0 + tx] = tv[tx][d];
  }
}

// ---------------- causal flash attention v8 (unchanged) ----------------
__global__ __launch_bounds__(256) void attn_kernel(const u16* __restrict__ Q, const u16* __restrict__ Kc,
                             const u16* __restrict__ Vt, u16* __restrict__ ctx)
{
  __shared__ u16 lK[2][64*128];
  __shared__ u16 lV[2][128*64];
  __shared__ u16 P[4*16*68];
  int id = blockIdx.x;
  int qt = 31 - (id >> 5);    // heavy blocks dispatched first
  int h  = id & 31;
  int tid = threadIdx.x;
  int lane = tid & 63;
  int wave = tid >> 6;
  int lr = lane & 15, lg = lane >> 4;
  int q0 = qt*64 + wave*16;   // this wave's strip
  int q  = q0 + lr;
  const u16* Qh = Q  + (size_t)h*SEQL*HDIM;
  const u16* Kh = Kc + (size_t)h*SEQL*HDIM;
  const u16* Vh = Vt + (size_t)h*HDIM*SEQL;
  u16* Pw = &P[wave*1088];

  bf16x8 qf[4];
  #pragma unroll
  for (int k32=0;k32<4;k32++)
    qf[k32] = *(const bf16x8*)&Qh[(size_t)(q0+lr)*HDIM + k32*32 + lg*8];

  f32x4 o[8] = {};
  float mrun = -1e30f, lrun = 0.f;

  int nt = qt + 1;   // 64-key tiles

  #define STAGE64(BUF, T0) do {                                             \
    _Pragma("unroll")                                                       \
    for (int i=0;i<4;i++){                                                  \
      int c = i*256 + tid;                                                  \
      int row = c >> 4, b = c & 15;                                         \
      int bp = b ^ (row & 7);                                               \
      gload_lds16(Kh + (size_t)((T0) + row)*HDIM + bp*8, &lK[BUF][c*8]);    \
    }                                                                       \
    _Pragma("unroll")                                                       \
    for (int i=0;i<4;i++){                                                  \
      int c = i*256 + tid;                                                  \
      int dd = c >> 3, b = c & 7;                                           \
      int bp = b ^ (dd & 7);                                                \
      gload_lds16(Vh + (size_t)dd*SEQL + (T0) + bp*8, &lV[BUF][c*8]);       \
    }                                                                       \
  } while(0)

  STAGE64(0, 0);
  __syncthreads();

  for (int t = 0; t < nt; ++t){
    int t0 = t*64;
    int cur = t & 1;
    if (t+1 < nt) STAGE64(cur^1, t0+64);   // prefetch overlaps compute

    const u16* Kt  = &lK[cur][0];
    const u16* Vtl = &lV[cur][0];

    // ---- QK^T (swapped: lane owns q-row q) ----
    f32x4 s4[4] = {};
    #pragma unroll
    for (int g=0; g<4; g++){
      int r = g*16 + lr;
      #pragma unroll
      for (int k32=0;k32<4;k32++){
        bf16x8 kf = *(const bf16x8*)&Kt[r*128 + ((((k32<<2)|lg) ^ (lr&7)))*8];
        s4[g] = __builtin_amdgcn_mfma_f32_16x16x32_bf16(kf, qf[k32], s4[g], 0, 0, 0);
      }
    }

    // ---- softmax ----
    float sv[16];
    #pragma unroll
    for (int g=0;g<4;g++){
      #pragma unroll
      for (int j=0;j<4;j++) sv[g*4+j] = s4[g][j];
    }
    if (t0 + 63 > q0){   // diagonal tile: apply causal mask
      int kb = t0 + lg*4;
      #pragma unroll
      for (int g=0;g<4;g++){
        #pragma unroll
        for (int j=0;j<4;j++)
          sv[g*4+j] = (kb + g*16 + j > q) ? -1e30f : sv[g*4+j];
      }
    }
    float mx = fmaxf(
      fmaxf(fmaxf(fmaxf(sv[0],sv[1]),fmaxf(sv[2],sv[3])),
            fmaxf(fmaxf(sv[4],sv[5]),fmaxf(sv[6],sv[7]))),
      fmaxf(fmaxf(fmaxf(sv[8],sv[9]),fmaxf(sv[10],sv[11])),
            fmaxf(fmaxf(sv[12],sv[13]),fmaxf(sv[14],sv[15]))));
    mx = fmaxf(mx, __shfl_xor(mx, 16));
    mx = fmaxf(mx, __shfl_xor(mx, 32));
    if (!__all(mx <= mrun + 11.5415603f)){
      float mnew = fmaxf(mrun, mx);
      float scl = exp2_asm(mrun - mnew);
      lrun *= scl;
      mrun = mnew;
      float sj[4];
      #pragma unroll
      for (int j=0;j<4;j++) sj[j] = __shfl(scl, lg*4 + j);
      #pragma unroll
      for (int n=0;n<8;n++){
        #pragma unroll
        for (int j=0;j<4;j++) o[n][j] *= sj[j];
      }
    }
    float pr[16];
    #pragma unroll
    for (int i=0;i<16;i++) pr[i] = exp2_asm(sv[i] - mrun);
    float sm = (((pr[0]+pr[1]) + (pr[2]+pr[3])) + ((pr[4]+pr[5]) + (pr[6]+pr[7])))
             + (((pr[8]+pr[9]) + (pr[10]+pr[11])) + ((pr[12]+pr[13]) + (pr[14]+pr[15])));
    sm += __shfl_xor(sm, 16);
    sm += __shfl_xor(sm, 32);
    lrun += sm;
    #pragma unroll
    for (int g=0;g<4;g++){
      uint2 w;
      w.x = cvtpk_bf16(pr[g*4],   pr[g*4+1]);
      w.y = cvtpk_bf16(pr[g*4+2], pr[g*4+3]);
      *(uint2*)&Pw[lr*68 + g*16 + lg*4] = w;
    }
    bf16x8 pa0 = *(const bf16x8*)&Pw[lr*68 + lg*8];
    bf16x8 pa1 = *(const bf16x8*)&Pw[lr*68 + 32 + lg*8];

    // ---- PV ----
    #pragma unroll
    for (int n=0;n<8;n++){
      int dd = n*16 + lr;
      bf16x8 v0 = *(const bf16x8*)&Vtl[dd*64 + ((lg ^ (dd&7)))*8];
      bf16x8 v1 = *(const bf16x8*)&Vtl[dd*64 + (((4|lg) ^ (dd&7)))*8];
      o[n] = __builtin_amdgcn_mfma_f32_16x16x32_bf16(pa0, v0, o[n], 0, 0, 0);
      o[n] = __builtin_amdgcn_mfma_f32_16x16x32_bf16(pa1, v1, o[n], 0, 0, 0);
    }
    __syncthreads();
  }
  #undef STAGE64

  #pragma unroll
  for (int j=0;j<4;j++){
    float lj = __shfl(lrun, lg*4 + j);
    float inv = 1.f / lj;
    int srow = q0 + lg*4 + j;
    #pragma unroll
    for (int n=0;n<8;n++)
      ctx[(size_t)srow*HIDDEN + h*HDIM + n*16 + lr] = f2bf(o[n][j]*inv);
  }
}

extern "C" void kernel_launch(void* const* d_in, const int* in_sizes, int n_in,
                              void* d_out, int out_size, void* d_ws, size_t ws_size,
                              hipStream_t stream)
{
  const float* hs   = (const float*)d_in[0];
  const int*   pos  = (const int*)d_in[1];
  const float* Wqkv = (const float*)d_in[2];
  const float* bqkv = (const float*)d_in[3];
  const float* Wd   = (const float*)d_in[4];
  const float* bd   = (const float*)d_in[5];

  const size_t o_hs  = 0;
  const size_t o_qkv = 16777216;
  const size_t o_Wtq = 67108864;
  const size_t o_Q   = 67108864;
  const size_t o_K   = 83886080;
  const size_t o_Vt  = 117440512;
  const size_t o_Wtd = 134217728;
  const size_t need  = 167772160;
  if (ws_size < need){
    fprintf(stderr, "kernel_launch: ws too small: %zu < %zu\n", ws_size, need);
    return;
  }
  char* w = (char*)d_ws;
  u16* hsb = (u16*)(w + o_hs);
  u16* qkv = (u16*)(w + o_qkv);
  u16* ctx = (u16*)(w + o_qkv);
  u16* Wtq = (u16*)(w + o_Wtq);
  u16* Qs  = (u16*)(w + o_Q);
  u16* Ks  = (u16*)(w + o_K);
  u16* Vts = (u16*)(w + o_Vt);
  u16* Wtd = (u16*)(w + o_Wtd);

  const size_t g8_lds = 65536*sizeof(u16);     // 131072 B
  const size_t g3_lds = 3*24576*sizeof(u16);   // 147456 B

  cast_hs_kernel<<<dim3(4096), dim3(256), 0, stream>>>(hs, hsb, SEQL*HIDDEN/8);
  wtrans64_kernel<<<dim3(192,64), dim3(256), 0, stream>>>(Wqkv, Wtq, 12288, 4096);

  // QKV GEMM split for exact CU-rounds:
  gemm8_kernel<1><<<dim3(8*32), dim3(512), g8_lds, stream>>>(
      hsb, Wtq, bqkv, (void*)qkv, HIDDEN, 12288);
  gemm3_kernel<1><<<dim3(16*16), dim3(512), g3_lds, stream>>>(
      hsb, Wtq + (size_t)8192*HIDDEN, bqkv + 8192, (void*)(qkv + 8192),
      HIDDEN, 12288, 16);

  wtrans64_kernel<<<dim3(64,64), dim3(256), 0, stream>>>(Wd, Wtd, 4096, 4096);

  // fused rope + V-transpose
  rope2_kernel<<<dim3(SEQL/64, NHEADS), dim3(256), 0, stream>>>(qkv, pos, Qs, Ks, Vts);
  attn_kernel<<<dim3(1024), dim3(256), 0, stream>>>(Qs, Ks, Vts, ctx);

  // dense GEMM: [2048 x 4096] x [4096 x 4096]^T -> d_out f32 (1 exact CU-round)
  gemm3_kernel<0><<<dim3(16*16), dim3(512), g3_lds, stream>>>(
      ctx, Wtd, bd, d_out, HIDDEN, HIDDEN, 16);
}